// Round 1
// baseline (2184.466 us; speedup 1.0000x reference)
//
#include <hip/hip_runtime.h>
#include <cstdint>
#include <cstddef>

// ---- problem dims ----
#define BB    8
#define CCH   2
#define IMGD  256
#define PDIM  16
#define DD    1024
#define LLAY  8
#define NHEAD 16
#define DFFD  4096
#define NTOK  256
#define SD    257
#define HDD   64
#define MTOK  (BB*SD)      // 2056
#define MPAT  (BB*NTOK)    // 2048
#define MPAD  2176         // 17*128 row padding for bf16 activation buffers
#define KPAD  288          // padded key count for VT (cols 257..287 zeroed)

typedef unsigned short u16;
typedef __bf16 bf16x8 __attribute__((ext_vector_type(8)));
typedef float  f32x4  __attribute__((ext_vector_type(4)));

__device__ __forceinline__ u16 f2bf(float f) {
    uint32_t u = __float_as_uint(f);
    u += 0x7FFF + ((u >> 16) & 1);     // RNE
    return (u16)(u >> 16);
}
__device__ __forceinline__ int imin(int a, int b) { return a < b ? a : b; }

#define GLB(p)  ((const __attribute__((address_space(1))) void*)(uintptr_t)(p))
#define LDSP(p) ((__attribute__((address_space(3))) void*)(uint32_t)(uintptr_t)(p))

// =====================================================================
// bf16 MFMA GEMM, 128x128 tile, BK=32, 256 thr (4 waves 2x2, 64x64/wave).
// A [Mpad][K] bf16 row-major; BT [N][K] bf16. ACT: GELU. OBF: bf16 out.
// =====================================================================
template<int ACT, int OBF>
__global__ __launch_bounds__(256) void gemm128(
    const u16* __restrict__ A, const u16* __restrict__ BT,
    const float* __restrict__ bias, const float* __restrict__ Cin,
    void* __restrict__ Cout, int M, int N, int K)
{
    __shared__ u16 lds[8192];
    const int tid = threadIdx.x, wid = tid >> 6, lane = tid & 63;
    const int m0 = blockIdx.y * 128, n0 = blockIdx.x * 128;
    const int wm = (wid >> 1) * 64, wn = (wid & 1) * 64;
    const int srow = lane >> 2, scol = (lane & 3) * 8;
    const int l15 = lane & 15, loct = lane >> 4;

    f32x4 acc[4][4] = {};

    const size_t arow = (size_t)(m0 + wid * 16 + srow) * K + scol;
    const size_t brow = (size_t)(n0 + wid * 16 + srow) * K + scol;
    u16* ldsA = lds + wid * 512;
    u16* ldsB = lds + 4096 + wid * 512;

    for (int k0 = 0; k0 < K; k0 += 32) {
        __builtin_amdgcn_global_load_lds(GLB(A  + arow + k0),                 LDSP(ldsA),        16, 0, 0);
        __builtin_amdgcn_global_load_lds(GLB(A  + arow + (size_t)64*K + k0),  LDSP(ldsA + 2048), 16, 0, 0);
        __builtin_amdgcn_global_load_lds(GLB(BT + brow + k0),                 LDSP(ldsB),        16, 0, 0);
        __builtin_amdgcn_global_load_lds(GLB(BT + brow + (size_t)64*K + k0),  LDSP(ldsB + 2048), 16, 0, 0);
        __syncthreads();
        bf16x8 af[4], bfr[4];
        #pragma unroll
        for (int i = 0; i < 4; ++i)
            af[i] = *(const bf16x8*)(lds + (wm + i * 16 + l15) * 32 + loct * 8);
        #pragma unroll
        for (int j = 0; j < 4; ++j)
            bfr[j] = *(const bf16x8*)(lds + 4096 + (wn + j * 16 + l15) * 32 + loct * 8);
        #pragma unroll
        for (int i = 0; i < 4; ++i)
            #pragma unroll
            for (int j = 0; j < 4; ++j)
                acc[i][j] = __builtin_amdgcn_mfma_f32_16x16x32_bf16(af[i], bfr[j], acc[i][j], 0, 0, 0);
        __syncthreads();
    }

    #pragma unroll
    for (int j = 0; j < 4; ++j) {
        const int col = n0 + wn + j * 16 + l15;
        const float bv = bias[col];
        #pragma unroll
        for (int i = 0; i < 4; ++i) {
            const int rbase = m0 + wm + i * 16 + loct * 4;
            #pragma unroll
            for (int r = 0; r < 4; ++r) {
                const int row = rbase + r;
                if (row < M) {
                    float v = acc[i][j][r] + bv;
                    if (ACT) v = 0.5f * v * (1.f + erff(v * 0.70710678118654752f));
                    if (Cin) v += Cin[(size_t)row * N + col];
                    if (OBF) ((u16*)Cout)[(size_t)row * N + col] = f2bf(v);
                    else     ((float*)Cout)[(size_t)row * N + col] = v;
                }
            }
        }
    }
}

// =====================================================================
// Split-K bf16 MFMA GEMM, 128x128 tile, BK=32, SPLIT z-blocks over K.
// Accumulates partials into fp32 C via native atomics (C pre-holds the
// residual). bias added by split z==0 only.
// =====================================================================
template<int SPLIT>
__global__ __launch_bounds__(256) void gemm128_sk(
    const u16* __restrict__ A, const u16* __restrict__ BT,
    const float* __restrict__ bias, float* __restrict__ C,
    int M, int N, int K)
{
    __shared__ u16 lds[8192];
    const int tid = threadIdx.x, wid = tid >> 6, lane = tid & 63;
    const int m0 = blockIdx.y * 128, n0 = blockIdx.x * 128;
    const int wm = (wid >> 1) * 64, wn = (wid & 1) * 64;
    const int srow = lane >> 2, scol = (lane & 3) * 8;
    const int l15 = lane & 15, loct = lane >> 4;
    const int Ks = K / SPLIT;
    const int kb = blockIdx.z * Ks;

    f32x4 acc[4][4] = {};

    const size_t arow = (size_t)(m0 + wid * 16 + srow) * K + scol + kb;
    const size_t brow = (size_t)(n0 + wid * 16 + srow) * K + scol + kb;
    u16* ldsA = lds + wid * 512;
    u16* ldsB = lds + 4096 + wid * 512;

    for (int k0 = 0; k0 < Ks; k0 += 32) {
        __builtin_amdgcn_global_load_lds(GLB(A  + arow + k0),                 LDSP(ldsA),        16, 0, 0);
        __builtin_amdgcn_global_load_lds(GLB(A  + arow + (size_t)64*K + k0),  LDSP(ldsA + 2048), 16, 0, 0);
        __builtin_amdgcn_global_load_lds(GLB(BT + brow + k0),                 LDSP(ldsB),        16, 0, 0);
        __builtin_amdgcn_global_load_lds(GLB(BT + brow + (size_t)64*K + k0),  LDSP(ldsB + 2048), 16, 0, 0);
        __syncthreads();
        bf16x8 af[4], bfr[4];
        #pragma unroll
        for (int i = 0; i < 4; ++i)
            af[i] = *(const bf16x8*)(lds + (wm + i * 16 + l15) * 32 + loct * 8);
        #pragma unroll
        for (int j = 0; j < 4; ++j)
            bfr[j] = *(const bf16x8*)(lds + 4096 + (wn + j * 16 + l15) * 32 + loct * 8);
        #pragma unroll
        for (int i = 0; i < 4; ++i)
            #pragma unroll
            for (int j = 0; j < 4; ++j)
                acc[i][j] = __builtin_amdgcn_mfma_f32_16x16x32_bf16(af[i], bfr[j], acc[i][j], 0, 0, 0);
        __syncthreads();
    }

    const int z0 = (blockIdx.z == 0);
    #pragma unroll
    for (int j = 0; j < 4; ++j) {
        const int col = n0 + wn + j * 16 + l15;
        const float bv = z0 ? bias[col] : 0.f;
        #pragma unroll
        for (int i = 0; i < 4; ++i) {
            const int rbase = m0 + wm + i * 16 + loct * 4;
            #pragma unroll
            for (int r = 0; r < 4; ++r) {
                const int row = rbase + r;
                if (row < M)
                    unsafeAtomicAdd(&C[(size_t)row * N + col], acc[i][j][r] + bv);
            }
        }
    }
}

// =====================================================================
// QKV GEMM: same mainloop, N=3072. Bias select fused (q|k|v). Epilogue:
//   cols 0..2047   -> QKb [row][2048]        (q | k), bf16
//   cols 2048..3071-> VTg [(b*1024+hd)][KPAD] at col=key (V transposed), bf16
// =====================================================================
__global__ __launch_bounds__(256) void gemm_qkv(
    const u16* __restrict__ A, const u16* __restrict__ BT,
    const float* __restrict__ bq, const float* __restrict__ bk,
    const float* __restrict__ bvp,
    u16* __restrict__ QKb, u16* __restrict__ VTg, int M, int K)
{
    __shared__ u16 lds[8192];
    const int tid = threadIdx.x, wid = tid >> 6, lane = tid & 63;
    const int m0 = blockIdx.y * 128, n0 = blockIdx.x * 128;
    const int wm = (wid >> 1) * 64, wn = (wid & 1) * 64;
    const int srow = lane >> 2, scol = (lane & 3) * 8;
    const int l15 = lane & 15, loct = lane >> 4;

    f32x4 acc[4][4] = {};
    const size_t arow = (size_t)(m0 + wid * 16 + srow) * K + scol;
    const size_t brow = (size_t)(n0 + wid * 16 + srow) * K + scol;
    u16* ldsA = lds + wid * 512;
    u16* ldsB = lds + 4096 + wid * 512;

    for (int k0 = 0; k0 < K; k0 += 32) {
        __builtin_amdgcn_global_load_lds(GLB(A  + arow + k0),                 LDSP(ldsA),        16, 0, 0);
        __builtin_amdgcn_global_load_lds(GLB(A  + arow + (size_t)64*K + k0),  LDSP(ldsA + 2048), 16, 0, 0);
        __builtin_amdgcn_global_load_lds(GLB(BT + brow + k0),                 LDSP(ldsB),        16, 0, 0);
        __builtin_amdgcn_global_load_lds(GLB(BT + brow + (size_t)64*K + k0),  LDSP(ldsB + 2048), 16, 0, 0);
        __syncthreads();
        bf16x8 af[4], bfr[4];
        #pragma unroll
        for (int i = 0; i < 4; ++i)
            af[i] = *(const bf16x8*)(lds + (wm + i * 16 + l15) * 32 + loct * 8);
        #pragma unroll
        for (int j = 0; j < 4; ++j)
            bfr[j] = *(const bf16x8*)(lds + 4096 + (wn + j * 16 + l15) * 32 + loct * 8);
        #pragma unroll
        for (int i = 0; i < 4; ++i)
            #pragma unroll
            for (int j = 0; j < 4; ++j)
                acc[i][j] = __builtin_amdgcn_mfma_f32_16x16x32_bf16(af[i], bfr[j], acc[i][j], 0, 0, 0);
        __syncthreads();
    }

    #pragma unroll
    for (int j = 0; j < 4; ++j) {
        const int col = n0 + wn + j * 16 + l15;
        const float bval = (col < 1024) ? bq[col]
                         : (col < 2048) ? bk[col - 1024]
                                        : bvp[col - 2048];
        #pragma unroll
        for (int i = 0; i < 4; ++i) {
            const int rbase = m0 + wm + i * 16 + loct * 4;
            #pragma unroll
            for (int r = 0; r < 4; ++r) {
                const int row = rbase + r;
                if (row < M) {
                    const float v = acc[i][j][r] + bval;
                    if (col < 2048) {
                        QKb[(size_t)row * 2048 + col] = f2bf(v);
                    } else {
                        const int b = row / SD;
                        const int key = row - b * SD;
                        VTg[((size_t)b * 1024 + (col - 2048)) * KPAD + key] = f2bf(v);
                    }
                }
            }
        }
    }
}

// =====================================================================
// bf16 MFMA GEMM, 64x64 tile, BK=64, 256 thr (4 waves 2x2, 32x32/wave).
// =====================================================================
template<int ACT, int OBF>
__global__ __launch_bounds__(256) void gemm64(
    const u16* __restrict__ A, const u16* __restrict__ BT,
    const float* __restrict__ bias, const float* __restrict__ Cin,
    void* __restrict__ Cout, int M, int N, int K)
{
    __shared__ u16 lds[8192];
    const int tid = threadIdx.x, wid = tid >> 6, lane = tid & 63;
    const int m0 = blockIdx.y * 64, n0 = blockIdx.x * 64;
    const int wm = (wid >> 1) * 32, wn = (wid & 1) * 32;
    const int srow = lane >> 2, scol = (lane & 3) * 8;
    const int l15 = lane & 15, loct = lane >> 4;

    f32x4 acc[2][2] = {};
    const size_t arow = (size_t)(m0 + wid * 16 + srow) * K + scol;
    const size_t brow = (size_t)(n0 + wid * 16 + srow) * K + scol;
    u16* ldsA = lds + wid * 512;
    u16* ldsB = lds + 4096 + wid * 512;

    for (int k0 = 0; k0 < K; k0 += 64) {
        __builtin_amdgcn_global_load_lds(GLB(A  + arow + k0),      LDSP(ldsA),        16, 0, 0);
        __builtin_amdgcn_global_load_lds(GLB(A  + arow + k0 + 32), LDSP(ldsA + 2048), 16, 0, 0);
        __builtin_amdgcn_global_load_lds(GLB(BT + brow + k0),      LDSP(ldsB),        16, 0, 0);
        __builtin_amdgcn_global_load_lds(GLB(BT + brow + k0 + 32), LDSP(ldsB + 2048), 16, 0, 0);
        __syncthreads();
        #pragma unroll
        for (int t = 0; t < 2; ++t) {
            bf16x8 af[2], bfr[2];
            #pragma unroll
            for (int i = 0; i < 2; ++i)
                af[i] = *(const bf16x8*)(lds + t * 2048 + (wm + i * 16 + l15) * 32 + loct * 8);
            #pragma unroll
            for (int j = 0; j < 2; ++j)
                bfr[j] = *(const bf16x8*)(lds + 4096 + t * 2048 + (wn + j * 16 + l15) * 32 + loct * 8);
            #pragma unroll
            for (int i = 0; i < 2; ++i)
                #pragma unroll
                for (int j = 0; j < 2; ++j)
                    acc[i][j] = __builtin_amdgcn_mfma_f32_16x16x32_bf16(af[i], bfr[j], acc[i][j], 0, 0, 0);
        }
        __syncthreads();
    }

    #pragma unroll
    for (int j = 0; j < 2; ++j) {
        const int col = n0 + wn + j * 16 + l15;
        const float bv = bias[col];
        #pragma unroll
        for (int i = 0; i < 2; ++i) {
            const int rbase = m0 + wm + i * 16 + loct * 4;
            #pragma unroll
            for (int r = 0; r < 4; ++r) {
                const int row = rbase + r;
                if (row < M) {
                    float v = acc[i][j][r] + bv;
                    if (ACT) v = 0.5f * v * (1.f + erff(v * 0.70710678118654752f));
                    if (Cin) v += Cin[(size_t)row * N + col];
                    if (OBF) ((u16*)Cout)[(size_t)row * N + col] = f2bf(v);
                    else     ((float*)Cout)[(size_t)row * N + col] = v;
                }
            }
        }
    }
}

// =====================================================================
// Fused attention, one (b,h) per blockIdx.x, 64 q-rows per block (wave=16).
// =====================================================================
__global__ __launch_bounds__(256) void attn_fused(
    const u16* __restrict__ QKb, const u16* __restrict__ VTg,
    u16* __restrict__ O)
{
    __shared__ u16 P[4][16][296];          // 37.9 KB
    const int tid = threadIdx.x, wid = tid >> 6, lane = tid & 63;
    const int l15 = lane & 15, loct = lane >> 4;
    const int bh = blockIdx.x, b = bh >> 4, h = bh & 15;
    const int q0 = blockIdx.y * 64 + wid * 16;

    const size_t qkbase = (size_t)b * SD * 2048 + h * 64;
    const u16* qp = QKb + qkbase + (size_t)imin(q0 + l15, SD - 1) * 2048;
    const bf16x8 qf0 = *(const bf16x8*)(qp + loct * 8);
    const bf16x8 qf1 = *(const bf16x8*)(qp + 32 + loct * 8);

    f32x4 s[17];
    #pragma unroll
    for (int nt = 0; nt < 17; ++nt) {
        const u16* kp = QKb + qkbase + (size_t)imin(nt * 16 + l15, SD - 1) * 2048 + 1024;
        const bf16x8 kf0 = *(const bf16x8*)(kp + loct * 8);
        const bf16x8 kf1 = *(const bf16x8*)(kp + 32 + loct * 8);
        f32x4 a = {};
        a = __builtin_amdgcn_mfma_f32_16x16x32_bf16(qf0, kf0, a, 0, 0, 0);
        a = __builtin_amdgcn_mfma_f32_16x16x32_bf16(qf1, kf1, a, 0, 0, 0);
        s[nt] = a;
    }

    const float dec = logf(1.f - exp2f(-1.f - (float)h));
    const int qb = q0 + loct * 4;
    float rmax[4] = {-3.4e38f, -3.4e38f, -3.4e38f, -3.4e38f};
    #pragma unroll
    for (int nt = 0; nt < 17; ++nt) {
        const int key = nt * 16 + l15;
        #pragma unroll
        for (int r = 0; r < 4; ++r) {
            float v;
            if (key >= SD) {
                v = -1e30f;
            } else {
                v = s[nt][r] * 0.125f;
                const int q = qb + r;
                if (q > 0 && key > 0) {
                    const int nq = q - 1, nk = key - 1;
                    const int dist = abs((nq >> 4) - (nk >> 4)) + abs((nq & 15) - (nk & 15));
                    v += dec * (float)dist;
                }
            }
            s[nt][r] = v;
            rmax[r] = fmaxf(rmax[r], v);
        }
    }
    #pragma unroll
    for (int r = 0; r < 4; ++r) {
        #pragma unroll
        for (int m = 1; m < 16; m <<= 1) rmax[r] = fmaxf(rmax[r], __shfl_xor(rmax[r], m));
    }
    float rsum[4] = {0.f, 0.f, 0.f, 0.f};
    #pragma unroll
    for (int nt = 0; nt < 17; ++nt)
        #pragma unroll
        for (int r = 0; r < 4; ++r) {
            const float e = __expf(s[nt][r] - rmax[r]);
            s[nt][r] = e;
            rsum[r] += e;
        }
    #pragma unroll
    for (int r = 0; r < 4; ++r) {
        #pragma unroll
        for (int m = 1; m < 16; m <<= 1) rsum[r] += __shfl_xor(rsum[r], m);
        rsum[r] = 1.f / rsum[r];
    }
    #pragma unroll
    for (int nt = 0; nt < 17; ++nt)
        #pragma unroll
        for (int r = 0; r < 4; ++r)
            P[wid][loct * 4 + r][nt * 16 + l15] = f2bf(s[nt][r] * rsum[r]);
    {
        const int rr = lane >> 2, cc = (lane & 3) * 4;
        #pragma unroll
        for (int i = 0; i < 4; ++i) P[wid][rr][272 + cc + i] = 0;
    }

    f32x4 o[4] = {};
    const u16* vrow = VTg + ((size_t)b * 1024 + h * 64) * KPAD;
    #pragma unroll
    for (int ks = 0; ks < 9; ++ks) {
        const bf16x8 pf = *(const bf16x8*)&P[wid][l15][ks * 32 + loct * 8];
        #pragma unroll
        for (int j = 0; j < 4; ++j) {
            const bf16x8 vf = *(const bf16x8*)(vrow + (size_t)(j * 16 + l15) * KPAD + ks * 32 + loct * 8);
            o[j] = __builtin_amdgcn_mfma_f32_16x16x32_bf16(pf, vf, o[j], 0, 0, 0);
        }
    }
    #pragma unroll
    for (int j = 0; j < 4; ++j)
        #pragma unroll
        for (int r = 0; r < 4; ++r) {
            const int q = qb + r;
            if (q < SD) O[((size_t)(b * SD + q)) * DD + h * 64 + j * 16 + l15] = f2bf(o[j][r]);
        }
}

// =====================================================================
// Batched weight transpose+convert: W fp32 [K][N] (z-strided) ->
// WT bf16 [N][K] (z-strided). 32x32 tiles.
// =====================================================================
__global__ __launch_bounds__(256) void transpose_bf16_b(
    const float* __restrict__ W, u16* __restrict__ WT, int K, int N,
    size_t sstrideZ, size_t dstrideZ)
{
    __shared__ float t[32][33];
    const float* Wz = W + (size_t)blockIdx.z * sstrideZ;
    u16* WTz = WT + (size_t)blockIdx.z * dstrideZ;
    const int k0 = blockIdx.y * 32, n0 = blockIdx.x * 32;
    const int c = threadIdx.x & 31, rb = threadIdx.x >> 5;
    #pragma unroll
    for (int i = 0; i < 4; ++i) {
        const int r = rb + i * 8;
        t[r][c] = Wz[(size_t)(k0 + r) * N + n0 + c];
    }
    __syncthreads();
    #pragma unroll
    for (int i = 0; i < 4; ++i) {
        const int r = rb + i * 8;
        WTz[(size_t)(n0 + r) * K + k0 + c] = f2bf(t[c][r]);
    }
}

__global__ __launch_bounds__(256) void im2col_k(const float* __restrict__ imgs,
                                                u16* __restrict__ Ao)
{
    const int idx = blockIdx.x * 256 + threadIdx.x;
    const int k = idx & 511, m = idx >> 9;
    const int b = m >> 8, n = m & 255;
    const int hp = n >> 4, wp = n & 15;
    const int c = k >> 8, p = (k >> 4) & 15, q = k & 15;
    Ao[idx] = f2bf(imgs[(((size_t)b * CCH + c) * IMGD + hp * PDIM + p) * IMGD + wp * PDIM + q]);
}

__global__ __launch_bounds__(256) void build_x_k(const float* __restrict__ RES,
                                                 const float* __restrict__ cls,
                                                 float* __restrict__ X)
{
    const int idx = blockIdx.x * 256 + threadIdx.x;
    const int d = idx & 1023;
    const int r = idx >> 10;
    const int b = r / SD;
    const int s = r - b * SD;
    X[idx] = (s == 0) ? cls[d] : RES[((size_t)(b * NTOK + s - 1)) * DD + d];
}

template<int OBF>
__global__ __launch_bounds__(256) void ln_rows(const float* __restrict__ X,
                                               const float* __restrict__ w,
                                               const float* __restrict__ bsrc,
                                               void* __restrict__ Y)
{
    const int row = blockIdx.x;
    const int tid = threadIdx.x;
    const float* xr = X + (size_t)row * DD;
    const float4 v = *(const float4*)(xr + tid * 4);
    float s  = v.x + v.y + v.z + v.w;
    float s2 = v.x * v.x + v.y * v.y + v.z * v.z + v.w * v.w;
    #pragma unroll
    for (int off = 1; off < 64; off <<= 1) {
        s  += __shfl_xor(s, off);
        s2 += __shfl_xor(s2, off);
    }
    __shared__ float rs[4], rs2[4];
    if ((tid & 63) == 0) { rs[tid >> 6] = s; rs2[tid >> 6] = s2; }
    __syncthreads();
    s  = rs[0] + rs[1] + rs[2] + rs[3];
    s2 = rs2[0] + rs2[1] + rs2[2] + rs2[3];
    const float mu  = s * (1.f / 1024.f);
    const float var = fmaf(-mu, mu, s2 * (1.f / 1024.f));
    const float ri  = rsqrtf(var + 1e-5f);
    const float4 wv = *(const float4*)(w + tid * 4);
    const float4 bv = *(const float4*)(bsrc + tid * 4);
    float4 o;
    o.x = (v.x - mu) * ri * wv.x + bv.x;
    o.y = (v.y - mu) * ri * wv.y + bv.y;
    o.z = (v.z - mu) * ri * wv.z + bv.z;
    o.w = (v.w - mu) * ri * wv.w + bv.w;
    if (OBF) {
        ushort4 o4 = make_ushort4(f2bf(o.x), f2bf(o.y), f2bf(o.z), f2bf(o.w));
        *(ushort4*)((u16*)Y + (size_t)row * DD + tid * 4) = o4;
    } else {
        *(float4*)((float*)Y + (size_t)row * DD + tid * 4) = o;
    }
}

__global__ __launch_bounds__(256) void pgsa_k(const float* __restrict__ Xf,
                                              const float* __restrict__ RES,
                                              u16* __restrict__ TOK)
{
    const int bd = blockIdx.x;
    const int b = bd >> 10, dch = bd & 1023;
    const int n = threadIdx.x;
    const float t = Xf[((size_t)(b * SD + 1 + n)) * DD + dch];
    __shared__ float red[4];
    float s = t;
    #pragma unroll
    for (int off = 1; off < 64; off <<= 1) s += __shfl_xor(s, off);
    if ((n & 63) == 0) red[n >> 6] = s;
    __syncthreads();
    const float mu = (red[0] + red[1] + red[2] + red[3]) * (1.f / 256.f);
    const float xm = t - mu;
    const float xm2 = xm * xm;
    __syncthreads();
    float s2 = xm2;
    #pragma unroll
    for (int off = 1; off < 64; off <<= 1) s2 += __shfl_xor(s2, off);
    if ((n & 63) == 0) red[n >> 6] = s2;
    __syncthreads();
    const float tot2 = red[0] + red[1] + red[2] + red[3];
    const float y = xm2 / (4.f * (tot2 * (1.f / 255.f) + 1e-4f)) + 0.5f;
    const float sig = 1.f / (1.f + expf(-y));
    const size_t ri = ((size_t)b * NTOK + n) * DD + dch;
    TOK[ri] = f2bf(fmaf(t, sig, RES[ri]));
}

__global__ __launch_bounds__(256) void unpatch_k(const float* __restrict__ PRED,
                                                 float* __restrict__ out)
{
    const int idx = blockIdx.x * 256 + threadIdx.x;
    const int j = idx & 255, i = (idx >> 8) & 255;
    const int c = (idx >> 16) & 1, b = idx >> 17;
    const int hp = i >> 4, p = i & 15, wp = j >> 4, q = j & 15;
    out[idx] = PRED[((size_t)b * NTOK + hp * 16 + wp) * 512 + (p * 16 + q) * 2 + c];
}

// =====================================================================
extern "C" void kernel_launch(void* const* d_in, const int* in_sizes, int n_in,
                              void* d_out, int out_size, void* d_ws, size_t ws_size,
                              hipStream_t stream)
{
    const float* imgs     = (const float*)d_in[0];
    const float* patch_w  = (const float*)d_in[1];
    const float* patch_b  = (const float*)d_in[2];
    const float* cls_tok  = (const float*)d_in[3];
    const float* ln1_w    = (const float*)d_in[4];
    const float* ln1_b    = (const float*)d_in[5];
    const float* wq       = (const float*)d_in[6];
    const float* wk       = (const float*)d_in[7];
    const float* wv       = (const float*)d_in[8];
    const float* bq       = (const float*)d_in[9];
    const float* bk       = (const float*)d_in[10];
    const float* bv       = (const float*)d_in[11];
    const float* wo       = (const float*)d_in[12];
    const float* bo       = (const float*)d_in[13];
    const float* ln2_w    = (const float*)d_in[14];
    const float* ln2_b    = (const float*)d_in[15];
    const float* w1       = (const float*)d_in[16];
    const float* b1       = (const float*)d_in[17];
    const float* w2       = (const float*)d_in[18];
    const float* b2       = (const float*)d_in[19];
    const float* normf_w  = (const float*)d_in[20];
    const float* normf_b  = (const float*)d_in[21];
    const float* enpred_w = (const float*)d_in[22];
    const float* enpred_b = (const float*)d_in[23];
    float* out = (float*)d_out;

    // ---- workspace layout (~261 MB; harness poison fill shows ws = 512 MiB) ----
    char* w = (char*)d_ws;
    float* X     = (float*)w;            w += (size_t)MTOK * DD * 4;          //  8.42 MB
    float* RES   = (float*)w;            w += (size_t)MPAT * DD * 4;          //  8.39 MB
    u16*   QKb   = (u16*)w;              w += (size_t)MPAD * 2048 * 2;        //  8.91 MB (alias Hf fp32 8.42)
    u16*   VTg   = (u16*)w;              w += (size_t)BB * 1024 * KPAD * 2;   //  4.72 MB
    char*  UNION = w;                    w += (size_t)MPAD * DFFD * 2;        // 17.83 MB: im2col/GELUb/PRED
    u16*   Hb    = (u16*)w;              w += (size_t)MPAD * DD * 2;          //  4.46 MB (alias TOKb)
    u16*   Ob    = (u16*)w;              w += (size_t)MPAD * DD * 2;          //  4.46 MB
    u16*   WTqkv = (u16*)w;              w += (size_t)LLAY * 3072 * DD * 2;   // 50.33 MB
    u16*   WTwo  = (u16*)w;              w += (size_t)LLAY * DD * DD * 2;     // 16.78 MB
    u16*   WTw1  = (u16*)w;              w += (size_t)LLAY * DFFD * DD * 2;   // 67.11 MB
    u16*   WTw2  = (u16*)w;              w += (size_t)LLAY * DD * DFFD * 2;   // 67.11 MB
    u16*   WTpe  = (u16*)w;              w += (size_t)DD * 512 * 2;           //  1.05 MB
    u16*   WTen  = (u16*)w;              w += (size_t)512 * DD * 2;           //  1.05 MB

    u16*   IM2b  = (u16*)UNION;
    u16*   GELUb = (u16*)UNION;
    float* PRED  = (float*)UNION;
    float* Hf    = (float*)QKb;
    u16*   TOKb  = Hb;

    // zero VT pad cols (gemm_qkv writes only keys 0..256; pad must be 0)
    hipMemsetAsync(VTg, 0, (size_t)BB * 1024 * KPAD * 2, stream);

    // ---- all weight transposes hoisted & batched (8 launches replace 50) ----
    hipLaunchKernelGGL(transpose_bf16_b, dim3(DD / 32, 512 / 32, 1), dim3(256), 0, stream,
                       patch_w, WTpe, 512, DD, 0, 0);
    hipLaunchKernelGGL(transpose_bf16_b, dim3(32, 32, LLAY), dim3(256), 0, stream,
                       wq, WTqkv,                     DD, DD, (size_t)DD * DD, (size_t)3072 * DD);
    hipLaunchKernelGGL(transpose_bf16_b, dim3(32, 32, LLAY), dim3(256), 0, stream,
                       wk, WTqkv + (size_t)1024 * DD, DD, DD, (size_t)DD * DD, (size_t)3072 * DD);
    hipLaunchKernelGGL(transpose_bf16_b, dim3(32, 32, LLAY), dim3(256), 0, stream,
                       wv, WTqkv + (size_t)2048 * DD, DD, DD, (size_t)DD * DD, (size_t)3072 * DD);
    hipLaunchKernelGGL(transpose_bf16_b, dim3(32, 32, LLAY), dim3(256), 0, stream,
                       wo, WTwo, DD, DD, (size_t)DD * DD, (size_t)DD * DD);
    hipLaunchKernelGGL(transpose_bf16_b, dim3(DFFD / 32, DD / 32, LLAY), dim3(256), 0, stream,
                       w1, WTw1, DD, DFFD, (size_t)DD * DFFD, (size_t)DFFD * DD);
    hipLaunchKernelGGL(transpose_bf16_b, dim3(DD / 32, DFFD / 32, LLAY), dim3(256), 0, stream,
                       w2, WTw2, DFFD, DD, (size_t)DFFD * DD, (size_t)DD * DFFD);
    hipLaunchKernelGGL(transpose_bf16_b, dim3(512 / 32, DD / 32, 1), dim3(256), 0, stream,
                       enpred_w, WTen, DD, 512, 0, 0);

    // ---- patch embed ----
    hipLaunchKernelGGL(im2col_k, dim3(4096), dim3(256), 0, stream, imgs, IM2b);
    hipLaunchKernelGGL((gemm64<0,0>), dim3(DD / 64, MPAT / 64), dim3(256), 0, stream,
                       IM2b, WTpe, patch_b, (const float*)nullptr, (void*)RES, MPAT, DD, 512);
    hipLaunchKernelGGL(build_x_k, dim3(MTOK * DD / 256), dim3(256), 0, stream, RES, cls_tok, X);

    // ---- transformer layers ----
    for (int i = 0; i < LLAY; ++i) {
        hipLaunchKernelGGL((ln_rows<1>), dim3(MTOK), dim3(256), 0, stream,
                           X, ln1_w + i * DD, ln1_b + i * DD, (void*)Hb);
        hipLaunchKernelGGL(gemm_qkv, dim3(3072 / 128, 17), dim3(256), 0, stream,
                           Hb, WTqkv + (size_t)i * 3072 * DD,
                           bq + i * DD, bk + i * DD, bv + i * DD, QKb, VTg, MTOK, DD);
        hipLaunchKernelGGL(attn_fused, dim3(BB * NHEAD, 5), dim3(256), 0, stream,
                           QKb, VTg, Ob);
        hipLaunchKernelGGL((gemm64<0,0>), dim3(DD / 64, 33), dim3(256), 0, stream,
                           Ob, WTwo + (size_t)i * DD * DD, bo + i * DD, X, (void*)X, MTOK, DD, DD);
        hipLaunchKernelGGL((ln_rows<1>), dim3(MTOK), dim3(256), 0, stream,
                           X, ln2_w + i * DD, ln2_b + i * DD, (void*)Hb);
        hipLaunchKernelGGL((gemm128<1,1>), dim3(DFFD / 128, 17), dim3(256), 0, stream,
                           Hb, WTw1 + (size_t)i * DFFD * DD, b1 + i * DFFD,
                           (const float*)nullptr, (void*)GELUb, MTOK, DFFD, DD);
        // MLP2: split-K=4 over K=4096, 128x128 tile, atomic fp32 accumulate
        // into X (which already holds the residual). 8x17x4 = 544 blocks.
        hipLaunchKernelGGL((gemm128_sk<4>), dim3(DD / 128, 17, 4), dim3(256), 0, stream,
                           GELUb, WTw2 + (size_t)i * DD * DFFD, b2 + i * DD, X, MTOK, DD, DFFD);
    }

    // ---- final LN + PGSA + predictor + unpatchify ----
    hipLaunchKernelGGL((ln_rows<0>), dim3(MTOK), dim3(256), 0, stream, X, normf_w, normf_b, (void*)Hf);
    hipLaunchKernelGGL(pgsa_k, dim3(BB * DD), dim3(256), 0, stream, Hf, RES, TOKb);
    hipLaunchKernelGGL((gemm64<0,0>), dim3(512 / 64, MPAT / 64), dim3(256), 0, stream,
                       TOKb, WTen, enpred_b, (const float*)nullptr, (void*)PRED, MPAT, 512, DD);
    hipLaunchKernelGGL(unpatch_k, dim3(4096), dim3(256), 0, stream, PRED, out);
}

// Round 2
// 1942.442 us; speedup vs baseline: 1.1246x; 1.1246x over previous
//
#include <hip/hip_runtime.h>
#include <cstdint>
#include <cstddef>

// ---- problem dims ----
#define BB    8
#define CCH   2
#define IMGD  256
#define PDIM  16
#define DD    1024
#define LLAY  8
#define NHEAD 16
#define DFFD  4096
#define NTOK  256
#define SD    257
#define HDD   64
#define MTOK  (BB*SD)      // 2056
#define MPAT  (BB*NTOK)    // 2048
#define MPAD  2176         // 17*128 row padding for bf16 activation buffers
#define KPAD  288          // padded key count for VT (cols 257..287 zeroed)

typedef unsigned short u16;
typedef __bf16 bf16x8 __attribute__((ext_vector_type(8)));
typedef float  f32x4  __attribute__((ext_vector_type(4)));

__device__ __forceinline__ u16 f2bf(float f) {
    uint32_t u = __float_as_uint(f);
    u += 0x7FFF + ((u >> 16) & 1);     // RNE
    return (u16)(u >> 16);
}
__device__ __forceinline__ int imin(int a, int b) { return a < b ? a : b; }

#define GLB(p)  ((const __attribute__((address_space(1))) void*)(uintptr_t)(p))
#define LDSP(p) ((__attribute__((address_space(3))) void*)(uint32_t)(uintptr_t)(p))

// =====================================================================
// 64x64 fp32->bf16 transpose tile helper. LDS float[64][65]: both phases
// conflict-free (65%32=1 -> consecutive lanes consecutive banks).
// Read: 256B/wave-instr; write: 128B/wave-instr.
// =====================================================================
__device__ __forceinline__ void tp64(const float* __restrict__ W,
                                     u16* __restrict__ WT, int K, int N,
                                     int k0, int n0, float (*t)[65])
{
    const int c = threadIdx.x & 63, r4 = threadIdx.x >> 6;
    #pragma unroll
    for (int i = 0; i < 16; ++i) {
        const int r = i * 4 + r4;
        t[r][c] = W[(size_t)(k0 + r) * N + n0 + c];
    }
    __syncthreads();
    #pragma unroll
    for (int i = 0; i < 16; ++i) {
        const int r = i * 4 + r4;
        WT[(size_t)(n0 + r) * K + k0 + c] = f2bf(t[c][r]);
    }
}

// Decode one of the 3072 per-layer transpose tiles:
// [0,768) wq/wk/wv -> WTqkv(+which*1024*DD)  16x16 tiles of 1024x1024
// [768,1024) wo -> WTwo                       16x16
// [1024,2048) w1 (K=1024,N=4096) -> WTw1      16x64
// [2048,3072) w2 (K=4096,N=1024) -> WTw2      64x16
__device__ __forceinline__ void tp_dispatch(
    int t, const float* wqN, const float* wkN, const float* wvN,
    const float* woN, const float* w1N, const float* w2N,
    u16* WTqkvN, u16* WTwoN, u16* WTw1N, u16* WTw2N, float (*tb)[65])
{
    if (t < 768) {
        const int which = t >> 8, local = t & 255;
        const float* W = which == 0 ? wqN : which == 1 ? wkN : wvN;
        tp64(W, WTqkvN + (size_t)which * 1024 * DD, DD, DD,
             (local >> 4) * 64, (local & 15) * 64, tb);
    } else if (t < 1024) {
        const int local = t - 768;
        tp64(woN, WTwoN, DD, DD, (local >> 4) * 64, (local & 15) * 64, tb);
    } else if (t < 2048) {
        const int local = t - 1024;
        tp64(w1N, WTw1N, DD, DFFD, (local >> 6) * 64, (local & 63) * 64, tb);
    } else {
        const int local = t - 2048;
        tp64(w2N, WTw2N, DFFD, DD, (local >> 4) * 64, (local & 15) * 64, tb);
    }
}

// =====================================================================
// MLP1 carrier: gemm128 GELU bf16-out (grid y<17) + next-layer weight
// transpose tiles (grid y in [17,113), 3072 tiles). N=DFFD, K=DD fixed.
// =====================================================================
__global__ __launch_bounds__(256) void mlp1_tp(
    const u16* __restrict__ A, const u16* __restrict__ BT,
    const float* __restrict__ bias, u16* __restrict__ Cout, int M,
    const float* __restrict__ wqN, const float* __restrict__ wkN,
    const float* __restrict__ wvN, const float* __restrict__ woN,
    const float* __restrict__ w1N, const float* __restrict__ w2N,
    u16* __restrict__ WTqkvN, u16* __restrict__ WTwoN,
    u16* __restrict__ WTw1N, u16* __restrict__ WTw2N)
{
    __shared__ float smem[64 * 65];       // 16.64 KB, aliased by both paths
    if (blockIdx.y >= 17) {
        const int t = (blockIdx.y - 17) * 32 + blockIdx.x;
        tp_dispatch(t, wqN, wkN, wvN, woN, w1N, w2N,
                    WTqkvN, WTwoN, WTw1N, WTw2N, (float(*)[65])smem);
        return;
    }
    u16* lds = (u16*)smem;
    const int N = DFFD, K = DD;
    const int tid = threadIdx.x, wid = tid >> 6, lane = tid & 63;
    const int m0 = blockIdx.y * 128, n0 = blockIdx.x * 128;
    const int wm = (wid >> 1) * 64, wn = (wid & 1) * 64;
    const int srow = lane >> 2, scol = (lane & 3) * 8;
    const int l15 = lane & 15, loct = lane >> 4;

    f32x4 acc[4][4] = {};
    const size_t arow = (size_t)(m0 + wid * 16 + srow) * K + scol;
    const size_t brow = (size_t)(n0 + wid * 16 + srow) * K + scol;
    u16* ldsA = lds + wid * 512;
    u16* ldsB = lds + 4096 + wid * 512;

    for (int k0 = 0; k0 < K; k0 += 32) {
        __builtin_amdgcn_global_load_lds(GLB(A  + arow + k0),                 LDSP(ldsA),        16, 0, 0);
        __builtin_amdgcn_global_load_lds(GLB(A  + arow + (size_t)64*K + k0),  LDSP(ldsA + 2048), 16, 0, 0);
        __builtin_amdgcn_global_load_lds(GLB(BT + brow + k0),                 LDSP(ldsB),        16, 0, 0);
        __builtin_amdgcn_global_load_lds(GLB(BT + brow + (size_t)64*K + k0),  LDSP(ldsB + 2048), 16, 0, 0);
        __syncthreads();
        bf16x8 af[4], bfr[4];
        #pragma unroll
        for (int i = 0; i < 4; ++i)
            af[i] = *(const bf16x8*)(lds + (wm + i * 16 + l15) * 32 + loct * 8);
        #pragma unroll
        for (int j = 0; j < 4; ++j)
            bfr[j] = *(const bf16x8*)(lds + 4096 + (wn + j * 16 + l15) * 32 + loct * 8);
        #pragma unroll
        for (int i = 0; i < 4; ++i)
            #pragma unroll
            for (int j = 0; j < 4; ++j)
                acc[i][j] = __builtin_amdgcn_mfma_f32_16x16x32_bf16(af[i], bfr[j], acc[i][j], 0, 0, 0);
        __syncthreads();
    }

    #pragma unroll
    for (int j = 0; j < 4; ++j) {
        const int col = n0 + wn + j * 16 + l15;
        const float bv = bias[col];
        #pragma unroll
        for (int i = 0; i < 4; ++i) {
            const int rbase = m0 + wm + i * 16 + loct * 4;
            #pragma unroll
            for (int r = 0; r < 4; ++r) {
                const int row = rbase + r;
                if (row < M) {
                    float v = acc[i][j][r] + bv;
                    v = 0.5f * v * (1.f + erff(v * 0.70710678118654752f));
                    Cout[(size_t)row * N + col] = f2bf(v);
                }
            }
        }
    }
}

// =====================================================================
// Patch-embed carrier: gemm64 fp32-out (grid y<32; M=MPAT,N=DD,K=512)
// + layer-0 weight transpose tiles (grid y in [32,224)).
// =====================================================================
__global__ __launch_bounds__(256) void patch_tp(
    const u16* __restrict__ A, const u16* __restrict__ BT,
    const float* __restrict__ bias, float* __restrict__ Cout,
    const float* __restrict__ wq0, const float* __restrict__ wk0,
    const float* __restrict__ wv0, const float* __restrict__ wo0,
    const float* __restrict__ w10, const float* __restrict__ w20,
    u16* __restrict__ WTqkv0, u16* __restrict__ WTwo0,
    u16* __restrict__ WTw10, u16* __restrict__ WTw20)
{
    __shared__ float smem[64 * 65];
    if (blockIdx.y >= 32) {
        const int t = (blockIdx.y - 32) * 16 + blockIdx.x;
        tp_dispatch(t, wq0, wk0, wv0, wo0, w10, w20,
                    WTqkv0, WTwo0, WTw10, WTw20, (float(*)[65])smem);
        return;
    }
    u16* lds = (u16*)smem;
    const int N = DD, K = 512;
    const int tid = threadIdx.x, wid = tid >> 6, lane = tid & 63;
    const int m0 = blockIdx.y * 64, n0 = blockIdx.x * 64;
    const int wm = (wid >> 1) * 32, wn = (wid & 1) * 32;
    const int srow = lane >> 2, scol = (lane & 3) * 8;
    const int l15 = lane & 15, loct = lane >> 4;

    f32x4 acc[2][2] = {};
    const size_t arow = (size_t)(m0 + wid * 16 + srow) * K + scol;
    const size_t brow = (size_t)(n0 + wid * 16 + srow) * K + scol;
    u16* ldsA = lds + wid * 512;
    u16* ldsB = lds + 4096 + wid * 512;

    for (int k0 = 0; k0 < K; k0 += 64) {
        __builtin_amdgcn_global_load_lds(GLB(A  + arow + k0),      LDSP(ldsA),        16, 0, 0);
        __builtin_amdgcn_global_load_lds(GLB(A  + arow + k0 + 32), LDSP(ldsA + 2048), 16, 0, 0);
        __builtin_amdgcn_global_load_lds(GLB(BT + brow + k0),      LDSP(ldsB),        16, 0, 0);
        __builtin_amdgcn_global_load_lds(GLB(BT + brow + k0 + 32), LDSP(ldsB + 2048), 16, 0, 0);
        __syncthreads();
        #pragma unroll
        for (int t = 0; t < 2; ++t) {
            bf16x8 af[2], bfr[2];
            #pragma unroll
            for (int i = 0; i < 2; ++i)
                af[i] = *(const bf16x8*)(lds + t * 2048 + (wm + i * 16 + l15) * 32 + loct * 8);
            #pragma unroll
            for (int j = 0; j < 2; ++j)
                bfr[j] = *(const bf16x8*)(lds + 4096 + t * 2048 + (wn + j * 16 + l15) * 32 + loct * 8);
            #pragma unroll
            for (int i = 0; i < 2; ++i)
                #pragma unroll
                for (int j = 0; j < 2; ++j)
                    acc[i][j] = __builtin_amdgcn_mfma_f32_16x16x32_bf16(af[i], bfr[j], acc[i][j], 0, 0, 0);
        }
        __syncthreads();
    }

    #pragma unroll
    for (int j = 0; j < 2; ++j) {
        const int col = n0 + wn + j * 16 + l15;
        const float bv = bias[col];
        #pragma unroll
        for (int i = 0; i < 2; ++i) {
            const int rbase = m0 + wm + i * 16 + loct * 4;
            #pragma unroll
            for (int r = 0; r < 4; ++r) {
                const int row = rbase + r;
                Cout[(size_t)row * N + col] = acc[i][j][r] + bv;
            }
        }
    }
}

// =====================================================================
// QKV GEMM: 128x128 mainloop, N=3072. Bias select fused (q|k|v). Epilogue:
//   cols 0..2047   -> QKb [row][2048]        (q | k), bf16
//   cols 2048..3071-> VTg [(b*1024+hd)][KPAD] at col=key (V transposed), bf16
// =====================================================================
__global__ __launch_bounds__(256) void gemm_qkv(
    const u16* __restrict__ A, const u16* __restrict__ BT,
    const float* __restrict__ bq, const float* __restrict__ bk,
    const float* __restrict__ bvp,
    u16* __restrict__ QKb, u16* __restrict__ VTg, int M, int K)
{
    __shared__ u16 lds[8192];
    const int tid = threadIdx.x, wid = tid >> 6, lane = tid & 63;
    const int m0 = blockIdx.y * 128, n0 = blockIdx.x * 128;
    const int wm = (wid >> 1) * 64, wn = (wid & 1) * 64;
    const int srow = lane >> 2, scol = (lane & 3) * 8;
    const int l15 = lane & 15, loct = lane >> 4;

    f32x4 acc[4][4] = {};
    const size_t arow = (size_t)(m0 + wid * 16 + srow) * K + scol;
    const size_t brow = (size_t)(n0 + wid * 16 + srow) * K + scol;
    u16* ldsA = lds + wid * 512;
    u16* ldsB = lds + 4096 + wid * 512;

    for (int k0 = 0; k0 < K; k0 += 32) {
        __builtin_amdgcn_global_load_lds(GLB(A  + arow + k0),                 LDSP(ldsA),        16, 0, 0);
        __builtin_amdgcn_global_load_lds(GLB(A  + arow + (size_t)64*K + k0),  LDSP(ldsA + 2048), 16, 0, 0);
        __builtin_amdgcn_global_load_lds(GLB(BT + brow + k0),                 LDSP(ldsB),        16, 0, 0);
        __builtin_amdgcn_global_load_lds(GLB(BT + brow + (size_t)64*K + k0),  LDSP(ldsB + 2048), 16, 0, 0);
        __syncthreads();
        bf16x8 af[4], bfr[4];
        #pragma unroll
        for (int i = 0; i < 4; ++i)
            af[i] = *(const bf16x8*)(lds + (wm + i * 16 + l15) * 32 + loct * 8);
        #pragma unroll
        for (int j = 0; j < 4; ++j)
            bfr[j] = *(const bf16x8*)(lds + 4096 + (wn + j * 16 + l15) * 32 + loct * 8);
        #pragma unroll
        for (int i = 0; i < 4; ++i)
            #pragma unroll
            for (int j = 0; j < 4; ++j)
                acc[i][j] = __builtin_amdgcn_mfma_f32_16x16x32_bf16(af[i], bfr[j], acc[i][j], 0, 0, 0);
        __syncthreads();
    }

    #pragma unroll
    for (int j = 0; j < 4; ++j) {
        const int col = n0 + wn + j * 16 + l15;
        const float bval = (col < 1024) ? bq[col]
                         : (col < 2048) ? bk[col - 1024]
                                        : bvp[col - 2048];
        #pragma unroll
        for (int i = 0; i < 4; ++i) {
            const int rbase = m0 + wm + i * 16 + loct * 4;
            #pragma unroll
            for (int r = 0; r < 4; ++r) {
                const int row = rbase + r;
                if (row < M) {
                    const float v = acc[i][j][r] + bval;
                    if (col < 2048) {
                        QKb[(size_t)row * 2048 + col] = f2bf(v);
                    } else {
                        const int b = row / SD;
                        const int key = row - b * SD;
                        VTg[((size_t)b * 1024 + (col - 2048)) * KPAD + key] = f2bf(v);
                    }
                }
            }
        }
    }
}

// =====================================================================
// bf16 MFMA GEMM, 64x64 tile, BK=64, 256 thr (4 waves 2x2, 32x32/wave).
// =====================================================================
template<int ACT, int OBF>
__global__ __launch_bounds__(256) void gemm64(
    const u16* __restrict__ A, const u16* __restrict__ BT,
    const float* __restrict__ bias, const float* __restrict__ Cin,
    void* __restrict__ Cout, int M, int N, int K)
{
    __shared__ u16 lds[8192];
    const int tid = threadIdx.x, wid = tid >> 6, lane = tid & 63;
    const int m0 = blockIdx.y * 64, n0 = blockIdx.x * 64;
    const int wm = (wid >> 1) * 32, wn = (wid & 1) * 32;
    const int srow = lane >> 2, scol = (lane & 3) * 8;
    const int l15 = lane & 15, loct = lane >> 4;

    f32x4 acc[2][2] = {};
    const size_t arow = (size_t)(m0 + wid * 16 + srow) * K + scol;
    const size_t brow = (size_t)(n0 + wid * 16 + srow) * K + scol;
    u16* ldsA = lds + wid * 512;
    u16* ldsB = lds + 4096 + wid * 512;

    for (int k0 = 0; k0 < K; k0 += 64) {
        __builtin_amdgcn_global_load_lds(GLB(A  + arow + k0),      LDSP(ldsA),        16, 0, 0);
        __builtin_amdgcn_global_load_lds(GLB(A  + arow + k0 + 32), LDSP(ldsA + 2048), 16, 0, 0);
        __builtin_amdgcn_global_load_lds(GLB(BT + brow + k0),      LDSP(ldsB),        16, 0, 0);
        __builtin_amdgcn_global_load_lds(GLB(BT + brow + k0 + 32), LDSP(ldsB + 2048), 16, 0, 0);
        __syncthreads();
        #pragma unroll
        for (int t = 0; t < 2; ++t) {
            bf16x8 af[2], bfr[2];
            #pragma unroll
            for (int i = 0; i < 2; ++i)
                af[i] = *(const bf16x8*)(lds + t * 2048 + (wm + i * 16 + l15) * 32 + loct * 8);
            #pragma unroll
            for (int j = 0; j < 2; ++j)
                bfr[j] = *(const bf16x8*)(lds + 4096 + t * 2048 + (wn + j * 16 + l15) * 32 + loct * 8);
            #pragma unroll
            for (int i = 0; i < 2; ++i)
                #pragma unroll
                for (int j = 0; j < 2; ++j)
                    acc[i][j] = __builtin_amdgcn_mfma_f32_16x16x32_bf16(af[i], bfr[j], acc[i][j], 0, 0, 0);
        }
        __syncthreads();
    }

    #pragma unroll
    for (int j = 0; j < 2; ++j) {
        const int col = n0 + wn + j * 16 + l15;
        const float bv = bias[col];
        #pragma unroll
        for (int i = 0; i < 2; ++i) {
            const int rbase = m0 + wm + i * 16 + loct * 4;
            #pragma unroll
            for (int r = 0; r < 4; ++r) {
                const int row = rbase + r;
                if (row < M) {
                    float v = acc[i][j][r] + bv;
                    if (ACT) v = 0.5f * v * (1.f + erff(v * 0.70710678118654752f));
                    if (Cin) v += Cin[(size_t)row * N + col];
                    if (OBF) ((u16*)Cout)[(size_t)row * N + col] = f2bf(v);
                    else     ((float*)Cout)[(size_t)row * N + col] = v;
                }
            }
        }
    }
}

// =====================================================================
// Fused attention, one (b,h) per blockIdx.x, 64 q-rows per block (wave=16).
// =====================================================================
__global__ __launch_bounds__(256) void attn_fused(
    const u16* __restrict__ QKb, const u16* __restrict__ VTg,
    u16* __restrict__ O)
{
    __shared__ u16 P[4][16][296];          // 37.9 KB
    const int tid = threadIdx.x, wid = tid >> 6, lane = tid & 63;
    const int l15 = lane & 15, loct = lane >> 4;
    const int bh = blockIdx.x, b = bh >> 4, h = bh & 15;
    const int q0 = blockIdx.y * 64 + wid * 16;

    const size_t qkbase = (size_t)b * SD * 2048 + h * 64;
    const u16* qp = QKb + qkbase + (size_t)imin(q0 + l15, SD - 1) * 2048;
    const bf16x8 qf0 = *(const bf16x8*)(qp + loct * 8);
    const bf16x8 qf1 = *(const bf16x8*)(qp + 32 + loct * 8);

    f32x4 s[17];
    #pragma unroll
    for (int nt = 0; nt < 17; ++nt) {
        const u16* kp = QKb + qkbase + (size_t)imin(nt * 16 + l15, SD - 1) * 2048 + 1024;
        const bf16x8 kf0 = *(const bf16x8*)(kp + loct * 8);
        const bf16x8 kf1 = *(const bf16x8*)(kp + 32 + loct * 8);
        f32x4 a = {};
        a = __builtin_amdgcn_mfma_f32_16x16x32_bf16(qf0, kf0, a, 0, 0, 0);
        a = __builtin_amdgcn_mfma_f32_16x16x32_bf16(qf1, kf1, a, 0, 0, 0);
        s[nt] = a;
    }

    const float dec = logf(1.f - exp2f(-1.f - (float)h));
    const int qb = q0 + loct * 4;
    float rmax[4] = {-3.4e38f, -3.4e38f, -3.4e38f, -3.4e38f};
    #pragma unroll
    for (int nt = 0; nt < 17; ++nt) {
        const int key = nt * 16 + l15;
        #pragma unroll
        for (int r = 0; r < 4; ++r) {
            float v;
            if (key >= SD) {
                v = -1e30f;
            } else {
                v = s[nt][r] * 0.125f;
                const int q = qb + r;
                if (q > 0 && key > 0) {
                    const int nq = q - 1, nk = key - 1;
                    const int dist = abs((nq >> 4) - (nk >> 4)) + abs((nq & 15) - (nk & 15));
                    v += dec * (float)dist;
                }
            }
            s[nt][r] = v;
            rmax[r] = fmaxf(rmax[r], v);
        }
    }
    #pragma unroll
    for (int r = 0; r < 4; ++r) {
        #pragma unroll
        for (int m = 1; m < 16; m <<= 1) rmax[r] = fmaxf(rmax[r], __shfl_xor(rmax[r], m));
    }
    float rsum[4] = {0.f, 0.f, 0.f, 0.f};
    #pragma unroll
    for (int nt = 0; nt < 17; ++nt)
        #pragma unroll
        for (int r = 0; r < 4; ++r) {
            const float e = __expf(s[nt][r] - rmax[r]);
            s[nt][r] = e;
            rsum[r] += e;
        }
    #pragma unroll
    for (int r = 0; r < 4; ++r) {
        #pragma unroll
        for (int m = 1; m < 16; m <<= 1) rsum[r] += __shfl_xor(rsum[r], m);
        rsum[r] = 1.f / rsum[r];
    }
    #pragma unroll
    for (int nt = 0; nt < 17; ++nt)
        #pragma unroll
        for (int r = 0; r < 4; ++r)
            P[wid][loct * 4 + r][nt * 16 + l15] = f2bf(s[nt][r] * rsum[r]);
    {
        const int rr = lane >> 2, cc = (lane & 3) * 4;
        #pragma unroll
        for (int i = 0; i < 4; ++i) P[wid][rr][272 + cc + i] = 0;
    }

    f32x4 o[4] = {};
    const u16* vrow = VTg + ((size_t)b * 1024 + h * 64) * KPAD;
    #pragma unroll
    for (int ks = 0; ks < 9; ++ks) {
        const bf16x8 pf = *(const bf16x8*)&P[wid][l15][ks * 32 + loct * 8];
        #pragma unroll
        for (int j = 0; j < 4; ++j) {
            const bf16x8 vf = *(const bf16x8*)(vrow + (size_t)(j * 16 + l15) * KPAD + ks * 32 + loct * 8);
            o[j] = __builtin_amdgcn_mfma_f32_16x16x32_bf16(pf, vf, o[j], 0, 0, 0);
        }
    }
    #pragma unroll
    for (int j = 0; j < 4; ++j)
        #pragma unroll
        for (int r = 0; r < 4; ++r) {
            const int q = qb + r;
            if (q < SD) O[((size_t)(b * SD + q)) * DD + h * 64 + j * 16 + l15] = f2bf(o[j][r]);
        }
}

// =====================================================================
// Standalone batched 64x64 transpose (prologue: patch_w, enpred_w).
// Grid (N/64, K/64, Z).
// =====================================================================
__global__ __launch_bounds__(256) void transpose_bf16_b(
    const float* __restrict__ W, u16* __restrict__ WT, int K, int N,
    size_t sstrideZ, size_t dstrideZ)
{
    __shared__ float t[64][65];
    tp64(W + (size_t)blockIdx.z * sstrideZ, WT + (size_t)blockIdx.z * dstrideZ,
         K, N, blockIdx.y * 64, blockIdx.x * 64, t);
}

__global__ __launch_bounds__(256) void im2col_k(const float* __restrict__ imgs,
                                                u16* __restrict__ Ao)
{
    const int idx = blockIdx.x * 256 + threadIdx.x;
    const int k = idx & 511, m = idx >> 9;
    const int b = m >> 8, n = m & 255;
    const int hp = n >> 4, wp = n & 15;
    const int c = k >> 8, p = (k >> 4) & 15, q = k & 15;
    Ao[idx] = f2bf(imgs[(((size_t)b * CCH + c) * IMGD + hp * PDIM + p) * IMGD + wp * PDIM + q]);
}

__global__ __launch_bounds__(256) void build_x_k(const float* __restrict__ RES,
                                                 const float* __restrict__ cls,
                                                 float* __restrict__ X)
{
    const int idx = blockIdx.x * 256 + threadIdx.x;
    const int d = idx & 1023;
    const int r = idx >> 10;
    const int b = r / SD;
    const int s = r - b * SD;
    X[idx] = (s == 0) ? cls[d] : RES[((size_t)(b * NTOK + s - 1)) * DD + d];
}

// =====================================================================
// LayerNorm: one wave per row, 4 rows per block. No LDS, no barriers.
// =====================================================================
template<int OBF>
__global__ __launch_bounds__(256) void ln_rows(const float* __restrict__ X,
                                               const float* __restrict__ w,
                                               const float* __restrict__ bsrc,
                                               void* __restrict__ Y)
{
    const int wid = threadIdx.x >> 6, lane = threadIdx.x & 63;
    const int row = blockIdx.x * 4 + wid;
    const float* xr = X + (size_t)row * DD;
    float4 v[4];
    float s = 0.f, s2 = 0.f;
    #pragma unroll
    for (int i = 0; i < 4; ++i) {
        v[i] = *(const float4*)(xr + (i * 64 + lane) * 4);
        s  += v[i].x + v[i].y + v[i].z + v[i].w;
        s2 += v[i].x * v[i].x + v[i].y * v[i].y + v[i].z * v[i].z + v[i].w * v[i].w;
    }
    #pragma unroll
    for (int off = 1; off < 64; off <<= 1) {
        s  += __shfl_xor(s, off);
        s2 += __shfl_xor(s2, off);
    }
    const float mu  = s * (1.f / 1024.f);
    const float var = fmaf(-mu, mu, s2 * (1.f / 1024.f));
    const float ri  = rsqrtf(var + 1e-5f);
    #pragma unroll
    for (int i = 0; i < 4; ++i) {
        const float4 wv = *(const float4*)(w + (i * 64 + lane) * 4);
        const float4 bv = *(const float4*)(bsrc + (i * 64 + lane) * 4);
        float4 o;
        o.x = (v[i].x - mu) * ri * wv.x + bv.x;
        o.y = (v[i].y - mu) * ri * wv.y + bv.y;
        o.z = (v[i].z - mu) * ri * wv.z + bv.z;
        o.w = (v[i].w - mu) * ri * wv.w + bv.w;
        if (OBF) {
            ushort4 o4 = make_ushort4(f2bf(o.x), f2bf(o.y), f2bf(o.z), f2bf(o.w));
            *(ushort4*)((u16*)Y + (size_t)row * DD + (i * 64 + lane) * 4) = o4;
        } else {
            *(float4*)((float*)Y + (size_t)row * DD + (i * 64 + lane) * 4) = o;
        }
    }
}

__global__ __launch_bounds__(256) void pgsa_k(const float* __restrict__ Xf,
                                              const float* __restrict__ RES,
                                              u16* __restrict__ TOK)
{
    const int bd = blockIdx.x;
    const int b = bd >> 10, dch = bd & 1023;
    const int n = threadIdx.x;
    const float t = Xf[((size_t)(b * SD + 1 + n)) * DD + dch];
    __shared__ float red[4];
    float s = t;
    #pragma unroll
    for (int off = 1; off < 64; off <<= 1) s += __shfl_xor(s, off);
    if ((n & 63) == 0) red[n >> 6] = s;
    __syncthreads();
    const float mu = (red[0] + red[1] + red[2] + red[3]) * (1.f / 256.f);
    const float xm = t - mu;
    const float xm2 = xm * xm;
    __syncthreads();
    float s2 = xm2;
    #pragma unroll
    for (int off = 1; off < 64; off <<= 1) s2 += __shfl_xor(s2, off);
    if ((n & 63) == 0) red[n >> 6] = s2;
    __syncthreads();
    const float tot2 = red[0] + red[1] + red[2] + red[3];
    const float y = xm2 / (4.f * (tot2 * (1.f / 255.f) + 1e-4f)) + 0.5f;
    const float sig = 1.f / (1.f + expf(-y));
    const size_t ri = ((size_t)b * NTOK + n) * DD + dch;
    TOK[ri] = f2bf(fmaf(t, sig, RES[ri]));
}

__global__ __launch_bounds__(256) void unpatch_k(const float* __restrict__ PRED,
                                                 float* __restrict__ out)
{
    const int idx = blockIdx.x * 256 + threadIdx.x;
    const int j = idx & 255, i = (idx >> 8) & 255;
    const int c = (idx >> 16) & 1, b = idx >> 17;
    const int hp = i >> 4, p = i & 15, wp = j >> 4, q = j & 15;
    out[idx] = PRED[((size_t)b * NTOK + hp * 16 + wp) * 512 + (p * 16 + q) * 2 + c];
}

// =====================================================================
extern "C" void kernel_launch(void* const* d_in, const int* in_sizes, int n_in,
                              void* d_out, int out_size, void* d_ws, size_t ws_size,
                              hipStream_t stream)
{
    const float* imgs     = (const float*)d_in[0];
    const float* patch_w  = (const float*)d_in[1];
    const float* patch_b  = (const float*)d_in[2];
    const float* cls_tok  = (const float*)d_in[3];
    const float* ln1_w    = (const float*)d_in[4];
    const float* ln1_b    = (const float*)d_in[5];
    const float* wq       = (const float*)d_in[6];
    const float* wk       = (const float*)d_in[7];
    const float* wv       = (const float*)d_in[8];
    const float* bq       = (const float*)d_in[9];
    const float* bk       = (const float*)d_in[10];
    const float* bv       = (const float*)d_in[11];
    const float* wo       = (const float*)d_in[12];
    const float* bo       = (const float*)d_in[13];
    const float* ln2_w    = (const float*)d_in[14];
    const float* ln2_b    = (const float*)d_in[15];
    const float* w1       = (const float*)d_in[16];
    const float* b1       = (const float*)d_in[17];
    const float* w2       = (const float*)d_in[18];
    const float* b2       = (const float*)d_in[19];
    const float* normf_w  = (const float*)d_in[20];
    const float* normf_b  = (const float*)d_in[21];
    const float* enpred_w = (const float*)d_in[22];
    const float* enpred_b = (const float*)d_in[23];
    float* out = (float*)d_out;

    // ---- workspace layout (~261 MB; ws = 512 MiB) ----
    char* w = (char*)d_ws;
    float* X     = (float*)w;            w += (size_t)MTOK * DD * 4;          //  8.42 MB
    float* RES   = (float*)w;            w += (size_t)MPAT * DD * 4;          //  8.39 MB
    u16*   QKb   = (u16*)w;              w += (size_t)MPAD * 2048 * 2;        //  8.91 MB (alias Hf fp32 8.42)
    u16*   VTg   = (u16*)w;              w += (size_t)BB * 1024 * KPAD * 2;   //  4.72 MB
    char*  UNION = w;                    w += (size_t)MPAD * DFFD * 2;        // 17.83 MB: im2col/GELUb/PRED
    u16*   Hb    = (u16*)w;              w += (size_t)MPAD * DD * 2;          //  4.46 MB (alias TOKb)
    u16*   Ob    = (u16*)w;              w += (size_t)MPAD * DD * 2;          //  4.46 MB
    u16*   WTqkv = (u16*)w;              w += (size_t)LLAY * 3072 * DD * 2;   // 50.33 MB
    u16*   WTwo  = (u16*)w;              w += (size_t)LLAY * DD * DD * 2;     // 16.78 MB
    u16*   WTw1  = (u16*)w;              w += (size_t)LLAY * DFFD * DD * 2;   // 67.11 MB
    u16*   WTw2  = (u16*)w;              w += (size_t)LLAY * DD * DFFD * 2;   // 67.11 MB
    u16*   WTpe  = (u16*)w;              w += (size_t)DD * 512 * 2;           //  1.05 MB
    u16*   WTen  = (u16*)w;              w += (size_t)512 * DD * 2;           //  1.05 MB

    u16*   IM2b  = (u16*)UNION;
    u16*   GELUb = (u16*)UNION;
    float* PRED  = (float*)UNION;
    float* Hf    = (float*)QKb;
    u16*   TOKb  = Hb;

    // zero VT pad cols (gemm_qkv writes only keys 0..256; pad must be 0)
    hipMemsetAsync(VTg, 0, (size_t)BB * 1024 * KPAD * 2, stream);

    // ---- prologue: small transposes + im2col ----
    hipLaunchKernelGGL(transpose_bf16_b, dim3(DD / 64, 512 / 64, 1), dim3(256), 0, stream,
                       patch_w, WTpe, 512, DD, (size_t)0, (size_t)0);
    hipLaunchKernelGGL(transpose_bf16_b, dim3(512 / 64, DD / 64, 1), dim3(256), 0, stream,
                       enpred_w, WTen, DD, 512, (size_t)0, (size_t)0);
    hipLaunchKernelGGL(im2col_k, dim3(4096), dim3(256), 0, stream, imgs, IM2b);

    // ---- patch embed carrier (gemm64 + layer-0 weight transposes) ----
    hipLaunchKernelGGL(patch_tp, dim3(DD / 64, 32 + 192), dim3(256), 0, stream,
                       IM2b, WTpe, patch_b, RES,
                       wq, wk, wv, wo, w1, w2,
                       WTqkv, WTwo, WTw1, WTw2);
    hipLaunchKernelGGL(build_x_k, dim3(MTOK * DD / 256), dim3(256), 0, stream, RES, cls_tok, X);

    // ---- transformer layers ----
    for (int i = 0; i < LLAY; ++i) {
        hipLaunchKernelGGL((ln_rows<1>), dim3(MTOK / 4), dim3(256), 0, stream,
                           X, ln1_w + i * DD, ln1_b + i * DD, (void*)Hb);
        hipLaunchKernelGGL(gemm_qkv, dim3(3072 / 128, 17), dim3(256), 0, stream,
                           Hb, WTqkv + (size_t)i * 3072 * DD,
                           bq + i * DD, bk + i * DD, bv + i * DD, QKb, VTg, MTOK, DD);
        hipLaunchKernelGGL(attn_fused, dim3(BB * NHEAD, 5), dim3(256), 0, stream,
                           QKb, VTg, Ob);
        hipLaunchKernelGGL((gemm64<0,0>), dim3(DD / 64, 33), dim3(256), 0, stream,
                           Ob, WTwo + (size_t)i * DD * DD, bo + i * DD, X, (void*)X, MTOK, DD, DD);
        hipLaunchKernelGGL((ln_rows<1>), dim3(MTOK / 4), dim3(256), 0, stream,
                           X, ln2_w + i * DD, ln2_b + i * DD, (void*)Hb);
        // MLP1 carrier: layers 0..6 also transpose layer i+1's weights.
        if (i < LLAY - 1) {
            const size_t n1 = (size_t)(i + 1);
            hipLaunchKernelGGL(mlp1_tp, dim3(DFFD / 128, 17 + 96), dim3(256), 0, stream,
                               Hb, WTw1 + (size_t)i * DFFD * DD, b1 + i * DFFD, GELUb, MTOK,
                               wq + n1 * DD * DD, wk + n1 * DD * DD, wv + n1 * DD * DD,
                               wo + n1 * DD * DD, w1 + n1 * DD * DFFD, w2 + n1 * DFFD * DD,
                               WTqkv + n1 * 3072 * DD, WTwo + n1 * DD * DD,
                               WTw1 + n1 * DFFD * DD, WTw2 + n1 * DD * DFFD);
        } else {
            hipLaunchKernelGGL(mlp1_tp, dim3(DFFD / 128, 17), dim3(256), 0, stream,
                               Hb, WTw1 + (size_t)i * DFFD * DD, b1 + i * DFFD, GELUb, MTOK,
                               (const float*)nullptr, (const float*)nullptr, (const float*)nullptr,
                               (const float*)nullptr, (const float*)nullptr, (const float*)nullptr,
                               (u16*)nullptr, (u16*)nullptr, (u16*)nullptr, (u16*)nullptr);
        }
        hipLaunchKernelGGL((gemm64<0,0>), dim3(DD / 64, 33), dim3(256), 0, stream,
                           GELUb, WTw2 + (size_t)i * DD * DFFD, b2 + i * DD, X, (void*)X, MTOK, DD, DFFD);
    }

    // ---- final LN + PGSA + predictor + unpatchify ----
    hipLaunchKernelGGL((ln_rows<0>), dim3(MTOK / 4), dim3(256), 0, stream, X, normf_w, normf_b, (void*)Hf);
    hipLaunchKernelGGL(pgsa_k, dim3(BB * DD), dim3(256), 0, stream, Hf, RES, TOKb);
    hipLaunchKernelGGL((gemm64<0,0>), dim3(512 / 64, MPAT / 64), dim3(256), 0, stream,
                       TOKb, WTen, enpred_b, (const float*)nullptr, (void*)PRED, MPAT, 512, DD);
    hipLaunchKernelGGL(unpatch_k, dim3(4096), dim3(256), 0, stream, PRED, out);
}

// Round 3
// 1925.257 us; speedup vs baseline: 1.1346x; 1.0089x over previous
//
#include <hip/hip_runtime.h>
#include <cstdint>
#include <cstddef>

// ---- problem dims ----
#define BB    8
#define CCH   2
#define IMGD  256
#define PDIM  16
#define DD    1024
#define LLAY  8
#define NHEAD 16
#define DFFD  4096
#define NTOK  256
#define SD    257
#define HDD   64
#define MTOK  (BB*SD)      // 2056
#define MPAT  (BB*NTOK)    // 2048
#define MPAD  2176         // 17*128 row padding for bf16 activation buffers
#define KPAD  288          // padded key count for VT (cols 257..287 zeroed)
#define QSTR  3072         // QKVb row stride

typedef unsigned short u16;
typedef __bf16 bf16x8 __attribute__((ext_vector_type(8)));
typedef float  f32x4  __attribute__((ext_vector_type(4)));

__device__ __forceinline__ u16 f2bf(float f) {
    uint32_t u = __float_as_uint(f);
    u += 0x7FFF + ((u >> 16) & 1);     // RNE
    return (u16)(u >> 16);
}
__device__ __forceinline__ int imin(int a, int b) { return a < b ? a : b; }

#define GLB(p)  ((const __attribute__((address_space(1))) void*)(uintptr_t)(p))
#define LDSP(p) ((__attribute__((address_space(3))) void*)(uint32_t)(uintptr_t)(p))

// =====================================================================
// 64x64 fp32->bf16 transpose tile helper. LDS float[64][65]: both phases
// conflict-free.
// =====================================================================
__device__ __forceinline__ void tp64(const float* __restrict__ W,
                                     u16* __restrict__ WT, int K, int N,
                                     int k0, int n0, float (*t)[65])
{
    const int c = threadIdx.x & 63, r4 = threadIdx.x >> 6;
    #pragma unroll
    for (int i = 0; i < 16; ++i) {
        const int r = i * 4 + r4;
        t[r][c] = W[(size_t)(k0 + r) * N + n0 + c];
    }
    __syncthreads();
    #pragma unroll
    for (int i = 0; i < 16; ++i) {
        const int r = i * 4 + r4;
        WT[(size_t)(n0 + r) * K + k0 + c] = f2bf(t[c][r]);
    }
}

// Decode one of the 3072 per-layer transpose tiles.
__device__ __forceinline__ void tp_dispatch(
    int t, const float* wqN, const float* wkN, const float* wvN,
    const float* woN, const float* w1N, const float* w2N,
    u16* WTqkvN, u16* WTwoN, u16* WTw1N, u16* WTw2N, float (*tb)[65])
{
    if (t < 768) {
        const int which = t >> 8, local = t & 255;
        const float* W = which == 0 ? wqN : which == 1 ? wkN : wvN;
        tp64(W, WTqkvN + (size_t)which * 1024 * DD, DD, DD,
             (local >> 4) * 64, (local & 15) * 64, tb);
    } else if (t < 1024) {
        const int local = t - 768;
        tp64(woN, WTwoN, DD, DD, (local >> 4) * 64, (local & 15) * 64, tb);
    } else if (t < 2048) {
        const int local = t - 1024;
        tp64(w1N, WTw1N, DD, DFFD, (local >> 6) * 64, (local & 63) * 64, tb);
    } else {
        const int local = t - 2048;
        tp64(w2N, WTw2N, DFFD, DD, (local >> 4) * 64, (local & 15) * 64, tb);
    }
}

// =====================================================================
// MLP1 carrier: gemm128 GELU bf16-out (grid y<17) + next-layer weight
// transpose tiles (grid y in [17,113)). N=DFFD, K=DD fixed.
// =====================================================================
__global__ __launch_bounds__(256) void mlp1_tp(
    const u16* __restrict__ A, const u16* __restrict__ BT,
    const float* __restrict__ bias, u16* __restrict__ Cout, int M,
    const float* __restrict__ wqN, const float* __restrict__ wkN,
    const float* __restrict__ wvN, const float* __restrict__ woN,
    const float* __restrict__ w1N, const float* __restrict__ w2N,
    u16* __restrict__ WTqkvN, u16* __restrict__ WTwoN,
    u16* __restrict__ WTw1N, u16* __restrict__ WTw2N)
{
    __shared__ float smem[64 * 65];
    if (blockIdx.y >= 17) {
        const int t = (blockIdx.y - 17) * 32 + blockIdx.x;
        tp_dispatch(t, wqN, wkN, wvN, woN, w1N, w2N,
                    WTqkvN, WTwoN, WTw1N, WTw2N, (float(*)[65])smem);
        return;
    }
    u16* lds = (u16*)smem;
    const int N = DFFD, K = DD;
    const int tid = threadIdx.x, wid = tid >> 6, lane = tid & 63;
    const int m0 = blockIdx.y * 128, n0 = blockIdx.x * 128;
    const int wm = (wid >> 1) * 64, wn = (wid & 1) * 64;
    const int srow = lane >> 2, scol = (lane & 3) * 8;
    const int l15 = lane & 15, loct = lane >> 4;

    f32x4 acc[4][4] = {};
    const size_t arow = (size_t)(m0 + wid * 16 + srow) * K + scol;
    const size_t brow = (size_t)(n0 + wid * 16 + srow) * K + scol;
    u16* ldsA = lds + wid * 512;
    u16* ldsB = lds + 4096 + wid * 512;

    for (int k0 = 0; k0 < K; k0 += 32) {
        __builtin_amdgcn_global_load_lds(GLB(A  + arow + k0),                 LDSP(ldsA),        16, 0, 0);
        __builtin_amdgcn_global_load_lds(GLB(A  + arow + (size_t)64*K + k0),  LDSP(ldsA + 2048), 16, 0, 0);
        __builtin_amdgcn_global_load_lds(GLB(BT + brow + k0),                 LDSP(ldsB),        16, 0, 0);
        __builtin_amdgcn_global_load_lds(GLB(BT + brow + (size_t)64*K + k0),  LDSP(ldsB + 2048), 16, 0, 0);
        __syncthreads();
        bf16x8 af[4], bfr[4];
        #pragma unroll
        for (int i = 0; i < 4; ++i)
            af[i] = *(const bf16x8*)(lds + (wm + i * 16 + l15) * 32 + loct * 8);
        #pragma unroll
        for (int j = 0; j < 4; ++j)
            bfr[j] = *(const bf16x8*)(lds + 4096 + (wn + j * 16 + l15) * 32 + loct * 8);
        #pragma unroll
        for (int i = 0; i < 4; ++i)
            #pragma unroll
            for (int j = 0; j < 4; ++j)
                acc[i][j] = __builtin_amdgcn_mfma_f32_16x16x32_bf16(af[i], bfr[j], acc[i][j], 0, 0, 0);
        __syncthreads();
    }

    #pragma unroll
    for (int j = 0; j < 4; ++j) {
        const int col = n0 + wn + j * 16 + l15;
        const float bv = bias[col];
        #pragma unroll
        for (int i = 0; i < 4; ++i) {
            const int rbase = m0 + wm + i * 16 + loct * 4;
            #pragma unroll
            for (int r = 0; r < 4; ++r) {
                const int row = rbase + r;
                if (row < M) {
                    float v = acc[i][j][r] + bv;
                    v = 0.5f * v * (1.f + erff(v * 0.70710678118654752f));
                    Cout[(size_t)row * N + col] = f2bf(v);
                }
            }
        }
    }
}

// =====================================================================
// Split-K bf16 MFMA GEMM, 128x128 tile, BK=32, SPLIT z-blocks over K.
// Writes fp32 partials to P[z][M][N] (no bias; combine adds bias+residual).
// =====================================================================
template<int SPLIT>
__global__ __launch_bounds__(256) void gemm128_skp(
    const u16* __restrict__ A, const u16* __restrict__ BT,
    float* __restrict__ P, int M, int N, int K)
{
    __shared__ u16 lds[8192];
    const int tid = threadIdx.x, wid = tid >> 6, lane = tid & 63;
    const int m0 = blockIdx.y * 128, n0 = blockIdx.x * 128;
    const int wm = (wid >> 1) * 64, wn = (wid & 1) * 64;
    const int srow = lane >> 2, scol = (lane & 3) * 8;
    const int l15 = lane & 15, loct = lane >> 4;
    const int Ks = K / SPLIT;
    const int kb = blockIdx.z * Ks;

    f32x4 acc[4][4] = {};
    const size_t arow = (size_t)(m0 + wid * 16 + srow) * K + scol + kb;
    const size_t brow = (size_t)(n0 + wid * 16 + srow) * K + scol + kb;
    u16* ldsA = lds + wid * 512;
    u16* ldsB = lds + 4096 + wid * 512;

    for (int k0 = 0; k0 < Ks; k0 += 32) {
        __builtin_amdgcn_global_load_lds(GLB(A  + arow + k0),                 LDSP(ldsA),        16, 0, 0);
        __builtin_amdgcn_global_load_lds(GLB(A  + arow + (size_t)64*K + k0),  LDSP(ldsA + 2048), 16, 0, 0);
        __builtin_amdgcn_global_load_lds(GLB(BT + brow + k0),                 LDSP(ldsB),        16, 0, 0);
        __builtin_amdgcn_global_load_lds(GLB(BT + brow + (size_t)64*K + k0),  LDSP(ldsB + 2048), 16, 0, 0);
        __syncthreads();
        bf16x8 af[4], bfr[4];
        #pragma unroll
        for (int i = 0; i < 4; ++i)
            af[i] = *(const bf16x8*)(lds + (wm + i * 16 + l15) * 32 + loct * 8);
        #pragma unroll
        for (int j = 0; j < 4; ++j)
            bfr[j] = *(const bf16x8*)(lds + 4096 + (wn + j * 16 + l15) * 32 + loct * 8);
        #pragma unroll
        for (int i = 0; i < 4; ++i)
            #pragma unroll
            for (int j = 0; j < 4; ++j)
                acc[i][j] = __builtin_amdgcn_mfma_f32_16x16x32_bf16(af[i], bfr[j], acc[i][j], 0, 0, 0);
        __syncthreads();
    }

    float* Pz = P + (size_t)blockIdx.z * M * N;
    #pragma unroll
    for (int j = 0; j < 4; ++j) {
        const int col = n0 + wn + j * 16 + l15;
        #pragma unroll
        for (int i = 0; i < 4; ++i) {
            const int rbase = m0 + wm + i * 16 + loct * 4;
            #pragma unroll
            for (int r = 0; r < 4; ++r) {
                const int row = rbase + r;
                if (row < M) Pz[(size_t)row * N + col] = acc[i][j][r];
            }
        }
    }
}

// =====================================================================
// QKV GEMM: 128x128 mainloop, N=3072, bias select fused. Uniform
// coalesced epilogue: QKVb [row][3072] = q | k | v, bf16.
// =====================================================================
__global__ __launch_bounds__(256) void gemm_qkv(
    const u16* __restrict__ A, const u16* __restrict__ BT,
    const float* __restrict__ bq, const float* __restrict__ bk,
    const float* __restrict__ bvp,
    u16* __restrict__ QKVb, int M, int K)
{
    __shared__ u16 lds[8192];
    const int tid = threadIdx.x, wid = tid >> 6, lane = tid & 63;
    const int m0 = blockIdx.y * 128, n0 = blockIdx.x * 128;
    const int wm = (wid >> 1) * 64, wn = (wid & 1) * 64;
    const int srow = lane >> 2, scol = (lane & 3) * 8;
    const int l15 = lane & 15, loct = lane >> 4;

    f32x4 acc[4][4] = {};
    const size_t arow = (size_t)(m0 + wid * 16 + srow) * K + scol;
    const size_t brow = (size_t)(n0 + wid * 16 + srow) * K + scol;
    u16* ldsA = lds + wid * 512;
    u16* ldsB = lds + 4096 + wid * 512;

    for (int k0 = 0; k0 < K; k0 += 32) {
        __builtin_amdgcn_global_load_lds(GLB(A  + arow + k0),                 LDSP(ldsA),        16, 0, 0);
        __builtin_amdgcn_global_load_lds(GLB(A  + arow + (size_t)64*K + k0),  LDSP(ldsA + 2048), 16, 0, 0);
        __builtin_amdgcn_global_load_lds(GLB(BT + brow + k0),                 LDSP(ldsB),        16, 0, 0);
        __builtin_amdgcn_global_load_lds(GLB(BT + brow + (size_t)64*K + k0),  LDSP(ldsB + 2048), 16, 0, 0);
        __syncthreads();
        bf16x8 af[4], bfr[4];
        #pragma unroll
        for (int i = 0; i < 4; ++i)
            af[i] = *(const bf16x8*)(lds + (wm + i * 16 + l15) * 32 + loct * 8);
        #pragma unroll
        for (int j = 0; j < 4; ++j)
            bfr[j] = *(const bf16x8*)(lds + 4096 + (wn + j * 16 + l15) * 32 + loct * 8);
        #pragma unroll
        for (int i = 0; i < 4; ++i)
            #pragma unroll
            for (int j = 0; j < 4; ++j)
                acc[i][j] = __builtin_amdgcn_mfma_f32_16x16x32_bf16(af[i], bfr[j], acc[i][j], 0, 0, 0);
        __syncthreads();
    }

    #pragma unroll
    for (int j = 0; j < 4; ++j) {
        const int col = n0 + wn + j * 16 + l15;
        const float bval = (col < 1024) ? bq[col]
                         : (col < 2048) ? bk[col - 1024]
                                        : bvp[col - 2048];
        #pragma unroll
        for (int i = 0; i < 4; ++i) {
            const int rbase = m0 + wm + i * 16 + loct * 4;
            #pragma unroll
            for (int r = 0; r < 4; ++r) {
                const int row = rbase + r;
                if (row < M)
                    QKVb[(size_t)row * QSTR + col] = f2bf(acc[i][j][r] + bval);
            }
        }
    }
}

// =====================================================================
// V transpose: QKVb cols 2048..3071 -> VTg [(b*1024+hd)][KPAD] bf16,
// zero-filling key pads (257..KPAD-1). 64x64 tiles through LDS.
// Grid (16 hd-tiles, 5 key-tiles, 8 b).
// =====================================================================
__global__ __launch_bounds__(256) void vt_k(const u16* __restrict__ QKVb,
                                            u16* __restrict__ VTg)
{
    __shared__ u16 t[64][66];
    const int h0 = blockIdx.x * 64, k0 = blockIdx.y * 64, b = blockIdx.z;
    const int c = threadIdx.x & 63, r4 = threadIdx.x >> 6;
    #pragma unroll
    for (int i = 0; i < 16; ++i) {
        const int key = k0 + i * 4 + r4;
        t[i * 4 + r4][c] = (key < SD)
            ? QKVb[((size_t)(b * SD + key)) * QSTR + 2048 + h0 + c] : (u16)0;
    }
    __syncthreads();
    const int key = k0 + c;
    if (key < KPAD) {
        #pragma unroll
        for (int i = 0; i < 16; ++i) {
            const int hd = i * 4 + r4;
            VTg[((size_t)(b * 1024 + h0 + hd)) * KPAD + key] = t[c][hd];
        }
    }
}

// =====================================================================
// Patch-embed carrier: gemm64 fp32-out (grid y<32; M=MPAT,N=DD,K=512)
// + layer-0 weight transpose tiles (grid y in [32,224)).
// =====================================================================
__global__ __launch_bounds__(256) void patch_tp(
    const u16* __restrict__ A, const u16* __restrict__ BT,
    const float* __restrict__ bias, float* __restrict__ Cout,
    const float* __restrict__ wq0, const float* __restrict__ wk0,
    const float* __restrict__ wv0, const float* __restrict__ wo0,
    const float* __restrict__ w10, const float* __restrict__ w20,
    u16* __restrict__ WTqkv0, u16* __restrict__ WTwo0,
    u16* __restrict__ WTw10, u16* __restrict__ WTw20)
{
    __shared__ float smem[64 * 65];
    if (blockIdx.y >= 32) {
        const int t = (blockIdx.y - 32) * 16 + blockIdx.x;
        tp_dispatch(t, wq0, wk0, wv0, wo0, w10, w20,
                    WTqkv0, WTwo0, WTw10, WTw20, (float(*)[65])smem);
        return;
    }
    u16* lds = (u16*)smem;
    const int N = DD, K = 512;
    const int tid = threadIdx.x, wid = tid >> 6, lane = tid & 63;
    const int m0 = blockIdx.y * 64, n0 = blockIdx.x * 64;
    const int wm = (wid >> 1) * 32, wn = (wid & 1) * 32;
    const int srow = lane >> 2, scol = (lane & 3) * 8;
    const int l15 = lane & 15, loct = lane >> 4;

    f32x4 acc[2][2] = {};
    const size_t arow = (size_t)(m0 + wid * 16 + srow) * K + scol;
    const size_t brow = (size_t)(n0 + wid * 16 + srow) * K + scol;
    u16* ldsA = lds + wid * 512;
    u16* ldsB = lds + 4096 + wid * 512;

    for (int k0 = 0; k0 < K; k0 += 64) {
        __builtin_amdgcn_global_load_lds(GLB(A  + arow + k0),      LDSP(ldsA),        16, 0, 0);
        __builtin_amdgcn_global_load_lds(GLB(A  + arow + k0 + 32), LDSP(ldsA + 2048), 16, 0, 0);
        __builtin_amdgcn_global_load_lds(GLB(BT + brow + k0),      LDSP(ldsB),        16, 0, 0);
        __builtin_amdgcn_global_load_lds(GLB(BT + brow + k0 + 32), LDSP(ldsB + 2048), 16, 0, 0);
        __syncthreads();
        #pragma unroll
        for (int t = 0; t < 2; ++t) {
            bf16x8 af[2], bfr[2];
            #pragma unroll
            for (int i = 0; i < 2; ++i)
                af[i] = *(const bf16x8*)(lds + t * 2048 + (wm + i * 16 + l15) * 32 + loct * 8);
            #pragma unroll
            for (int j = 0; j < 2; ++j)
                bfr[j] = *(const bf16x8*)(lds + 4096 + t * 2048 + (wn + j * 16 + l15) * 32 + loct * 8);
            #pragma unroll
            for (int i = 0; i < 2; ++i)
                #pragma unroll
                for (int j = 0; j < 2; ++j)
                    acc[i][j] = __builtin_amdgcn_mfma_f32_16x16x32_bf16(af[i], bfr[j], acc[i][j], 0, 0, 0);
        }
        __syncthreads();
    }

    #pragma unroll
    for (int j = 0; j < 2; ++j) {
        const int col = n0 + wn + j * 16 + l15;
        const float bv = bias[col];
        #pragma unroll
        for (int i = 0; i < 2; ++i) {
            const int rbase = m0 + wm + i * 16 + loct * 4;
            #pragma unroll
            for (int r = 0; r < 4; ++r) {
                const int row = rbase + r;
                Cout[(size_t)row * N + col] = acc[i][j][r] + bv;
            }
        }
    }
}

// =====================================================================
// bf16 MFMA GEMM, 64x64 tile, BK=64 (proj, predictor).
// =====================================================================
template<int ACT, int OBF>
__global__ __launch_bounds__(256) void gemm64(
    const u16* __restrict__ A, const u16* __restrict__ BT,
    const float* __restrict__ bias, const float* __restrict__ Cin,
    void* __restrict__ Cout, int M, int N, int K)
{
    __shared__ u16 lds[8192];
    const int tid = threadIdx.x, wid = tid >> 6, lane = tid & 63;
    const int m0 = blockIdx.y * 64, n0 = blockIdx.x * 64;
    const int wm = (wid >> 1) * 32, wn = (wid & 1) * 32;
    const int srow = lane >> 2, scol = (lane & 3) * 8;
    const int l15 = lane & 15, loct = lane >> 4;

    f32x4 acc[2][2] = {};
    const size_t arow = (size_t)(m0 + wid * 16 + srow) * K + scol;
    const size_t brow = (size_t)(n0 + wid * 16 + srow) * K + scol;
    u16* ldsA = lds + wid * 512;
    u16* ldsB = lds + 4096 + wid * 512;

    for (int k0 = 0; k0 < K; k0 += 64) {
        __builtin_amdgcn_global_load_lds(GLB(A  + arow + k0),      LDSP(ldsA),        16, 0, 0);
        __builtin_amdgcn_global_load_lds(GLB(A  + arow + k0 + 32), LDSP(ldsA + 2048), 16, 0, 0);
        __builtin_amdgcn_global_load_lds(GLB(BT + brow + k0),      LDSP(ldsB),        16, 0, 0);
        __builtin_amdgcn_global_load_lds(GLB(BT + brow + k0 + 32), LDSP(ldsB + 2048), 16, 0, 0);
        __syncthreads();
        #pragma unroll
        for (int t = 0; t < 2; ++t) {
            bf16x8 af[2], bfr[2];
            #pragma unroll
            for (int i = 0; i < 2; ++i)
                af[i] = *(const bf16x8*)(lds + t * 2048 + (wm + i * 16 + l15) * 32 + loct * 8);
            #pragma unroll
            for (int j = 0; j < 2; ++j)
                bfr[j] = *(const bf16x8*)(lds + 4096 + t * 2048 + (wn + j * 16 + l15) * 32 + loct * 8);
            #pragma unroll
            for (int i = 0; i < 2; ++i)
                #pragma unroll
                for (int j = 0; j < 2; ++j)
                    acc[i][j] = __builtin_amdgcn_mfma_f32_16x16x32_bf16(af[i], bfr[j], acc[i][j], 0, 0, 0);
        }
        __syncthreads();
    }

    #pragma unroll
    for (int j = 0; j < 2; ++j) {
        const int col = n0 + wn + j * 16 + l15;
        const float bv = bias[col];
        #pragma unroll
        for (int i = 0; i < 2; ++i) {
            const int rbase = m0 + wm + i * 16 + loct * 4;
            #pragma unroll
            for (int r = 0; r < 4; ++r) {
                const int row = rbase + r;
                if (row < M) {
                    float v = acc[i][j][r] + bv;
                    if (ACT) v = 0.5f * v * (1.f + erff(v * 0.70710678118654752f));
                    if (Cin) v += Cin[(size_t)row * N + col];
                    if (OBF) ((u16*)Cout)[(size_t)row * N + col] = f2bf(v);
                    else     ((float*)Cout)[(size_t)row * N + col] = v;
                }
            }
        }
    }
}

// =====================================================================
// Fused attention, one (b,h) per blockIdx.x, 64 q-rows per block.
// =====================================================================
__global__ __launch_bounds__(256) void attn_fused(
    const u16* __restrict__ QKVb, const u16* __restrict__ VTg,
    u16* __restrict__ O)
{
    __shared__ u16 P[4][16][296];          // 37.9 KB
    const int tid = threadIdx.x, wid = tid >> 6, lane = tid & 63;
    const int l15 = lane & 15, loct = lane >> 4;
    const int bh = blockIdx.x, b = bh >> 4, h = bh & 15;
    const int q0 = blockIdx.y * 64 + wid * 16;

    const size_t qkbase = (size_t)b * SD * QSTR + h * 64;
    const u16* qp = QKVb + qkbase + (size_t)imin(q0 + l15, SD - 1) * QSTR;
    const bf16x8 qf0 = *(const bf16x8*)(qp + loct * 8);
    const bf16x8 qf1 = *(const bf16x8*)(qp + 32 + loct * 8);

    f32x4 s[17];
    #pragma unroll
    for (int nt = 0; nt < 17; ++nt) {
        const u16* kp = QKVb + qkbase + (size_t)imin(nt * 16 + l15, SD - 1) * QSTR + 1024;
        const bf16x8 kf0 = *(const bf16x8*)(kp + loct * 8);
        const bf16x8 kf1 = *(const bf16x8*)(kp + 32 + loct * 8);
        f32x4 a = {};
        a = __builtin_amdgcn_mfma_f32_16x16x32_bf16(qf0, kf0, a, 0, 0, 0);
        a = __builtin_amdgcn_mfma_f32_16x16x32_bf16(qf1, kf1, a, 0, 0, 0);
        s[nt] = a;
    }

    const float dec = logf(1.f - exp2f(-1.f - (float)h));
    const int qb = q0 + loct * 4;
    float rmax[4] = {-3.4e38f, -3.4e38f, -3.4e38f, -3.4e38f};
    #pragma unroll
    for (int nt = 0; nt < 17; ++nt) {
        const int key = nt * 16 + l15;
        #pragma unroll
        for (int r = 0; r < 4; ++r) {
            float v;
            if (key >= SD) {
                v = -1e30f;
            } else {
                v = s[nt][r] * 0.125f;
                const int q = qb + r;
                if (q > 0 && key > 0) {
                    const int nq = q - 1, nk = key - 1;
                    const int dist = abs((nq >> 4) - (nk >> 4)) + abs((nq & 15) - (nk & 15));
                    v += dec * (float)dist;
                }
            }
            s[nt][r] = v;
            rmax[r] = fmaxf(rmax[r], v);
        }
    }
    #pragma unroll
    for (int r = 0; r < 4; ++r) {
        #pragma unroll
        for (int m = 1; m < 16; m <<= 1) rmax[r] = fmaxf(rmax[r], __shfl_xor(rmax[r], m));
    }
    float rsum[4] = {0.f, 0.f, 0.f, 0.f};
    #pragma unroll
    for (int nt = 0; nt < 17; ++nt)
        #pragma unroll
        for (int r = 0; r < 4; ++r) {
            const float e = __expf(s[nt][r] - rmax[r]);
            s[nt][r] = e;
            rsum[r] += e;
        }
    #pragma unroll
    for (int r = 0; r < 4; ++r) {
        #pragma unroll
        for (int m = 1; m < 16; m <<= 1) rsum[r] += __shfl_xor(rsum[r], m);
        rsum[r] = 1.f / rsum[r];
    }
    #pragma unroll
    for (int nt = 0; nt < 17; ++nt)
        #pragma unroll
        for (int r = 0; r < 4; ++r)
            P[wid][loct * 4 + r][nt * 16 + l15] = f2bf(s[nt][r] * rsum[r]);
    {
        const int rr = lane >> 2, cc = (lane & 3) * 4;
        #pragma unroll
        for (int i = 0; i < 4; ++i) P[wid][rr][272 + cc + i] = 0;
    }

    f32x4 o[4] = {};
    const u16* vrow = VTg + ((size_t)b * 1024 + h * 64) * KPAD;
    #pragma unroll
    for (int ks = 0; ks < 9; ++ks) {
        const bf16x8 pf = *(const bf16x8*)&P[wid][l15][ks * 32 + loct * 8];
        #pragma unroll
        for (int j = 0; j < 4; ++j) {
            const bf16x8 vf = *(const bf16x8*)(vrow + (size_t)(j * 16 + l15) * KPAD + ks * 32 + loct * 8);
            o[j] = __builtin_amdgcn_mfma_f32_16x16x32_bf16(pf, vf, o[j], 0, 0, 0);
        }
    }
    #pragma unroll
    for (int j = 0; j < 4; ++j)
        #pragma unroll
        for (int r = 0; r < 4; ++r) {
            const int q = qb + r;
            if (q < SD) O[((size_t)(b * SD + q)) * DD + h * 64 + j * 16 + l15] = f2bf(o[j][r]);
        }
}

// =====================================================================
// Standalone batched 64x64 transpose (prologue: patch_w, enpred_w).
// =====================================================================
__global__ __launch_bounds__(256) void transpose_bf16_b(
    const float* __restrict__ W, u16* __restrict__ WT, int K, int N,
    size_t sstrideZ, size_t dstrideZ)
{
    __shared__ float t[64][65];
    tp64(W + (size_t)blockIdx.z * sstrideZ, WT + (size_t)blockIdx.z * dstrideZ,
         K, N, blockIdx.y * 64, blockIdx.x * 64, t);
}

__global__ __launch_bounds__(256) void im2col_k(const float* __restrict__ imgs,
                                                u16* __restrict__ Ao)
{
    const int idx = blockIdx.x * 256 + threadIdx.x;
    const int k = idx & 511, m = idx >> 9;
    const int b = m >> 8, n = m & 255;
    const int hp = n >> 4, wp = n & 15;
    const int c = k >> 8, p = (k >> 4) & 15, q = k & 15;
    Ao[idx] = f2bf(imgs[(((size_t)b * CCH + c) * IMGD + hp * PDIM + p) * IMGD + wp * PDIM + q]);
}

__global__ __launch_bounds__(256) void build_x_k(const float* __restrict__ RES,
                                                 const float* __restrict__ cls,
                                                 float* __restrict__ X)
{
    const int idx = blockIdx.x * 256 + threadIdx.x;
    const int d = idx & 1023;
    const int r = idx >> 10;
    const int b = r / SD;
    const int s = r - b * SD;
    X[idx] = (s == 0) ? cls[d] : RES[((size_t)(b * NTOK + s - 1)) * DD + d];
}

// =====================================================================
// LayerNorm, one wave per row, 4 rows/block. NP>0: first combine
// X += badd + sum(partials) (split-K MLP2 reduction fused in), write X.
// =====================================================================
template<int NP, int OBF>
__global__ __launch_bounds__(256) void ln_rows_c(
    float* __restrict__ X, const float* __restrict__ PB, size_t pstride,
    const float* __restrict__ badd,
    const float* __restrict__ w, const float* __restrict__ bsrc,
    void* __restrict__ Y)
{
    const int wid = threadIdx.x >> 6, lane = threadIdx.x & 63;
    const int row = blockIdx.x * 4 + wid;
    float* xr = X + (size_t)row * DD;
    float4 v[4];
    float s = 0.f, s2 = 0.f;
    #pragma unroll
    for (int i = 0; i < 4; ++i) {
        const int cc = (i * 64 + lane) * 4;
        v[i] = *(const float4*)(xr + cc);
        if (NP) {
            const float4 bb = *(const float4*)(badd + cc);
            v[i].x += bb.x; v[i].y += bb.y; v[i].z += bb.z; v[i].w += bb.w;
            #pragma unroll
            for (int p = 0; p < NP; ++p) {
                const float4 pv = *(const float4*)(PB + (size_t)p * pstride + (size_t)row * DD + cc);
                v[i].x += pv.x; v[i].y += pv.y; v[i].z += pv.z; v[i].w += pv.w;
            }
            *(float4*)(xr + cc) = v[i];
        }
        s  += v[i].x + v[i].y + v[i].z + v[i].w;
        s2 += v[i].x * v[i].x + v[i].y * v[i].y + v[i].z * v[i].z + v[i].w * v[i].w;
    }
    #pragma unroll
    for (int off = 1; off < 64; off <<= 1) {
        s  += __shfl_xor(s, off);
        s2 += __shfl_xor(s2, off);
    }
    const float mu  = s * (1.f / 1024.f);
    const float var = fmaf(-mu, mu, s2 * (1.f / 1024.f));
    const float ri  = rsqrtf(var + 1e-5f);
    #pragma unroll
    for (int i = 0; i < 4; ++i) {
        const int cc = (i * 64 + lane) * 4;
        const float4 wv = *(const float4*)(w + cc);
        const float4 bv = *(const float4*)(bsrc + cc);
        float4 o;
        o.x = (v[i].x - mu) * ri * wv.x + bv.x;
        o.y = (v[i].y - mu) * ri * wv.y + bv.y;
        o.z = (v[i].z - mu) * ri * wv.z + bv.z;
        o.w = (v[i].w - mu) * ri * wv.w + bv.w;
        if (OBF) {
            ushort4 o4 = make_ushort4(f2bf(o.x), f2bf(o.y), f2bf(o.z), f2bf(o.w));
            *(ushort4*)((u16*)Y + (size_t)row * DD + cc) = o4;
        } else {
            *(float4*)((float*)Y + (size_t)row * DD + cc) = o;
        }
    }
}

__global__ __launch_bounds__(256) void pgsa_k(const float* __restrict__ Xf,
                                              const float* __restrict__ RES,
                                              u16* __restrict__ TOK)
{
    const int bd = blockIdx.x;
    const int b = bd >> 10, dch = bd & 1023;
    const int n = threadIdx.x;
    const float t = Xf[((size_t)(b * SD + 1 + n)) * DD + dch];
    __shared__ float red[4];
    float s = t;
    #pragma unroll
    for (int off = 1; off < 64; off <<= 1) s += __shfl_xor(s, off);
    if ((n & 63) == 0) red[n >> 6] = s;
    __syncthreads();
    const float mu = (red[0] + red[1] + red[2] + red[3]) * (1.f / 256.f);
    const float xm = t - mu;
    const float xm2 = xm * xm;
    __syncthreads();
    float s2 = xm2;
    #pragma unroll
    for (int off = 1; off < 64; off <<= 1) s2 += __shfl_xor(s2, off);
    if ((n & 63) == 0) red[n >> 6] = s2;
    __syncthreads();
    const float tot2 = red[0] + red[1] + red[2] + red[3];
    const float y = xm2 / (4.f * (tot2 * (1.f / 255.f) + 1e-4f)) + 0.5f;
    const float sig = 1.f / (1.f + expf(-y));
    const size_t ri = ((size_t)b * NTOK + n) * DD + dch;
    TOK[ri] = f2bf(fmaf(t, sig, RES[ri]));
}

__global__ __launch_bounds__(256) void unpatch_k(const float* __restrict__ PRED,
                                                 float* __restrict__ out)
{
    const int idx = blockIdx.x * 256 + threadIdx.x;
    const int j = idx & 255, i = (idx >> 8) & 255;
    const int c = (idx >> 16) & 1, b = idx >> 17;
    const int hp = i >> 4, p = i & 15, wp = j >> 4, q = j & 15;
    out[idx] = PRED[((size_t)b * NTOK + hp * 16 + wp) * 512 + (p * 16 + q) * 2 + c];
}

// =====================================================================
extern "C" void kernel_launch(void* const* d_in, const int* in_sizes, int n_in,
                              void* d_out, int out_size, void* d_ws, size_t ws_size,
                              hipStream_t stream)
{
    const float* imgs     = (const float*)d_in[0];
    const float* patch_w  = (const float*)d_in[1];
    const float* patch_b  = (const float*)d_in[2];
    const float* cls_tok  = (const float*)d_in[3];
    const float* ln1_w    = (const float*)d_in[4];
    const float* ln1_b    = (const float*)d_in[5];
    const float* wq       = (const float*)d_in[6];
    const float* wk       = (const float*)d_in[7];
    const float* wv       = (const float*)d_in[8];
    const float* bq       = (const float*)d_in[9];
    const float* bk       = (const float*)d_in[10];
    const float* bv       = (const float*)d_in[11];
    const float* wo       = (const float*)d_in[12];
    const float* bo       = (const float*)d_in[13];
    const float* ln2_w    = (const float*)d_in[14];
    const float* ln2_b    = (const float*)d_in[15];
    const float* w1       = (const float*)d_in[16];
    const float* b1       = (const float*)d_in[17];
    const float* w2       = (const float*)d_in[18];
    const float* b2       = (const float*)d_in[19];
    const float* normf_w  = (const float*)d_in[20];
    const float* normf_b  = (const float*)d_in[21];
    const float* enpred_w = (const float*)d_in[22];
    const float* enpred_b = (const float*)d_in[23];
    float* out = (float*)d_out;

    // ---- workspace layout (~300 MB; ws = 512 MiB) ----
    char* w = (char*)d_ws;
    float* X     = (float*)w;            w += (size_t)MTOK * DD * 4;          //  8.42 MB
    float* RES   = (float*)w;            w += (size_t)MPAT * DD * 4;          //  8.39 MB
    u16*   QKVb  = (u16*)w;              w += (size_t)MPAD * QSTR * 2;        // 13.37 MB (alias Hf fp32 8.42)
    u16*   VTg   = (u16*)w;              w += (size_t)BB * 1024 * KPAD * 2;   //  4.72 MB
    char*  UNION = w;                    w += (size_t)MPAD * DFFD * 2;        // 17.83 MB: im2col/GELUb/PRED
    u16*   Hb    = (u16*)w;              w += (size_t)MPAD * DD * 2;          //  4.46 MB (alias TOKb)
    u16*   Ob    = (u16*)w;              w += (size_t)MPAD * DD * 2;          //  4.46 MB
    float* PART  = (float*)w;            w += (size_t)4 * MTOK * DD * 4;      // 33.69 MB (split-K partials)
    u16*   WTqkv = (u16*)w;              w += (size_t)LLAY * 3072 * DD * 2;   // 50.33 MB
    u16*   WTwo  = (u16*)w;              w += (size_t)LLAY * DD * DD * 2;     // 16.78 MB
    u16*   WTw1  = (u16*)w;              w += (size_t)LLAY * DFFD * DD * 2;   // 67.11 MB
    u16*   WTw2  = (u16*)w;              w += (size_t)LLAY * DD * DFFD * 2;   // 67.11 MB
    u16*   WTpe  = (u16*)w;              w += (size_t)DD * 512 * 2;           //  1.05 MB
    u16*   WTen  = (u16*)w;              w += (size_t)512 * DD * 2;           //  1.05 MB

    u16*   IM2b  = (u16*)UNION;
    u16*   GELUb = (u16*)UNION;
    float* PRED  = (float*)UNION;
    float* Hf    = (float*)QKVb;
    u16*   TOKb  = Hb;
    const size_t PSTR = (size_t)MTOK * DD;

    // ---- prologue: small transposes + im2col ----
    hipLaunchKernelGGL(transpose_bf16_b, dim3(DD / 64, 512 / 64, 1), dim3(256), 0, stream,
                       patch_w, WTpe, 512, DD, (size_t)0, (size_t)0);
    hipLaunchKernelGGL(transpose_bf16_b, dim3(512 / 64, DD / 64, 1), dim3(256), 0, stream,
                       enpred_w, WTen, DD, 512, (size_t)0, (size_t)0);
    hipLaunchKernelGGL(im2col_k, dim3(4096), dim3(256), 0, stream, imgs, IM2b);

    // ---- patch embed carrier (gemm64 + layer-0 weight transposes) ----
    hipLaunchKernelGGL(patch_tp, dim3(DD / 64, 32 + 192), dim3(256), 0, stream,
                       IM2b, WTpe, patch_b, RES,
                       wq, wk, wv, wo, w1, w2,
                       WTqkv, WTwo, WTw1, WTw2);
    hipLaunchKernelGGL(build_x_k, dim3(MTOK * DD / 256), dim3(256), 0, stream, RES, cls_tok, X);

    // ---- transformer layers ----
    for (int i = 0; i < LLAY; ++i) {
        // ln1; for i>0 it also combines the previous layer's MLP2 split-K
        // partials (+b2) into X first.
        if (i == 0)
            hipLaunchKernelGGL((ln_rows_c<0,1>), dim3(MTOK / 4), dim3(256), 0, stream,
                               X, (const float*)nullptr, (size_t)0, (const float*)nullptr,
                               ln1_w + i * DD, ln1_b + i * DD, (void*)Hb);
        else
            hipLaunchKernelGGL((ln_rows_c<4,1>), dim3(MTOK / 4), dim3(256), 0, stream,
                               X, PART, PSTR, b2 + (i - 1) * DD,
                               ln1_w + i * DD, ln1_b + i * DD, (void*)Hb);
        hipLaunchKernelGGL(gemm_qkv, dim3(3072 / 128, 17), dim3(256), 0, stream,
                           Hb, WTqkv + (size_t)i * 3072 * DD,
                           bq + i * DD, bk + i * DD, bv + i * DD, QKVb, MTOK, DD);
        hipLaunchKernelGGL(vt_k, dim3(16, 5, BB), dim3(256), 0, stream, QKVb, VTg);
        hipLaunchKernelGGL(attn_fused, dim3(BB * NHEAD, 5), dim3(256), 0, stream,
                           QKVb, VTg, Ob);
        hipLaunchKernelGGL((gemm64<0,0>), dim3(DD / 64, 33), dim3(256), 0, stream,
                           Ob, WTwo + (size_t)i * DD * DD, bo + i * DD, X, (void*)X, MTOK, DD, DD);
        hipLaunchKernelGGL((ln_rows_c<0,1>), dim3(MTOK / 4), dim3(256), 0, stream,
                           X, (const float*)nullptr, (size_t)0, (const float*)nullptr,
                           ln2_w + i * DD, ln2_b + i * DD, (void*)Hb);
        // MLP1 carrier: layers 0..6 also transpose layer i+1's weights.
        if (i < LLAY - 1) {
            const size_t n1 = (size_t)(i + 1);
            hipLaunchKernelGGL(mlp1_tp, dim3(DFFD / 128, 17 + 96), dim3(256), 0, stream,
                               Hb, WTw1 + (size_t)i * DFFD * DD, b1 + i * DFFD, GELUb, MTOK,
                               wq + n1 * DD * DD, wk + n1 * DD * DD, wv + n1 * DD * DD,
                               wo + n1 * DD * DD, w1 + n1 * DD * DFFD, w2 + n1 * DFFD * DD,
                               WTqkv + n1 * 3072 * DD, WTwo + n1 * DD * DD,
                               WTw1 + n1 * DFFD * DD, WTw2 + n1 * DD * DFFD);
        } else {
            hipLaunchKernelGGL(mlp1_tp, dim3(DFFD / 128, 17), dim3(256), 0, stream,
                               Hb, WTw1 + (size_t)i * DFFD * DD, b1 + i * DFFD, GELUb, MTOK,
                               (const float*)nullptr, (const float*)nullptr, (const float*)nullptr,
                               (const float*)nullptr, (const float*)nullptr, (const float*)nullptr,
                               (u16*)nullptr, (u16*)nullptr, (u16*)nullptr, (u16*)nullptr);
        }
        // MLP2: split-K=4 at 128x128 tile -> 544 blocks, fp32 partials.
        hipLaunchKernelGGL((gemm128_skp<4>), dim3(DD / 128, 17, 4), dim3(256), 0, stream,
                           GELUb, WTw2 + (size_t)i * DD * DFFD, PART, MTOK, DD, DFFD);
    }

    // ---- final LN (combines layer-7 MLP2) + PGSA + predictor + unpatchify ----
    hipLaunchKernelGGL((ln_rows_c<4,0>), dim3(MTOK / 4), dim3(256), 0, stream,
                       X, PART, PSTR, b2 + (LLAY - 1) * DD, normf_w, normf_b, (void*)Hf);
    hipLaunchKernelGGL(pgsa_k, dim3(BB * DD), dim3(256), 0, stream, Hf, RES, TOKb);
    hipLaunchKernelGGL((gemm64<0,0>), dim3(512 / 64, MPAT / 64), dim3(256), 0, stream,
                       TOKb, WTen, enpred_b, (const float*)nullptr, (void*)PRED, MPAT, 512, DD);
    hipLaunchKernelGGL(unpatch_k, dim3(4096), dim3(256), 0, stream, PRED, out);
}

// Round 4
// 1857.665 us; speedup vs baseline: 1.1759x; 1.0364x over previous
//
#include <hip/hip_runtime.h>
#include <cstdint>
#include <cstddef>

// ---- problem dims ----
#define BB    8
#define CCH   2
#define IMGD  256
#define PDIM  16
#define DD    1024
#define LLAY  8
#define NHEAD 16
#define DFFD  4096
#define NTOK  256
#define SD    257
#define HDD   64
#define MTOK  (BB*SD)      // 2056
#define MPAT  (BB*NTOK)    // 2048
#define MPAD  2176         // 17*128 row padding for bf16 activation buffers
#define KPAD  288          // padded key count for VT (cols 257..287 zeroed)

typedef unsigned short u16;
typedef __bf16 bf16x8 __attribute__((ext_vector_type(8)));
typedef float  f32x4  __attribute__((ext_vector_type(4)));

__device__ __forceinline__ u16 f2bf(float f) {
    uint32_t u = __float_as_uint(f);
    u += 0x7FFF + ((u >> 16) & 1);     // RNE
    return (u16)(u >> 16);
}
__device__ __forceinline__ int imin(int a, int b) { return a < b ? a : b; }

#define GLB(p)  ((const __attribute__((address_space(1))) void*)(uintptr_t)(p))
#define LDSP(p) ((__attribute__((address_space(3))) void*)(uint32_t)(uintptr_t)(p))

// =====================================================================
// 64x64 fp32->bf16 transpose tile helper. LDS float[64][65]: both phases
// conflict-free.
// =====================================================================
__device__ __forceinline__ void tp64(const float* __restrict__ W,
                                     u16* __restrict__ WT, int K, int N,
                                     int k0, int n0, float (*t)[65])
{
    const int c = threadIdx.x & 63, r4 = threadIdx.x >> 6;
    #pragma unroll
    for (int i = 0; i < 16; ++i) {
        const int r = i * 4 + r4;
        t[r][c] = W[(size_t)(k0 + r) * N + n0 + c];
    }
    __syncthreads();
    #pragma unroll
    for (int i = 0; i < 16; ++i) {
        const int r = i * 4 + r4;
        WT[(size_t)(n0 + r) * K + k0 + c] = f2bf(t[c][r]);
    }
}

// Decode one of the 3072 per-layer transpose tiles.
__device__ __forceinline__ void tp_dispatch(
    int t, const float* wqN, const float* wkN, const float* wvN,
    const float* woN, const float* w1N, const float* w2N,
    u16* WTqkvN, u16* WTwoN, u16* WTw1N, u16* WTw2N, float (*tb)[65])
{
    if (t < 768) {
        const int which = t >> 8, local = t & 255;
        const float* W = which == 0 ? wqN : which == 1 ? wkN : wvN;
        tp64(W, WTqkvN + (size_t)which * 1024 * DD, DD, DD,
             (local >> 4) * 64, (local & 15) * 64, tb);
    } else if (t < 1024) {
        const int local = t - 768;
        tp64(woN, WTwoN, DD, DD, (local >> 4) * 64, (local & 15) * 64, tb);
    } else if (t < 2048) {
        const int local = t - 1024;
        tp64(w1N, WTw1N, DD, DFFD, (local >> 6) * 64, (local & 63) * 64, tb);
    } else {
        const int local = t - 2048;
        tp64(w2N, WTw2N, DFFD, DD, (local >> 4) * 64, (local & 15) * 64, tb);
    }
}

// =====================================================================
// MLP1 carrier: gemm128 GELU bf16-out (grid y<17) + next-layer weight
// transpose tiles (grid y in [17,113)). N=DFFD, K=DD fixed.
// =====================================================================
__global__ __launch_bounds__(256) void mlp1_tp(
    const u16* __restrict__ A, const u16* __restrict__ BT,
    const float* __restrict__ bias, u16* __restrict__ Cout, int M,
    const float* __restrict__ wqN, const float* __restrict__ wkN,
    const float* __restrict__ wvN, const float* __restrict__ woN,
    const float* __restrict__ w1N, const float* __restrict__ w2N,
    u16* __restrict__ WTqkvN, u16* __restrict__ WTwoN,
    u16* __restrict__ WTw1N, u16* __restrict__ WTw2N)
{
    __shared__ float smem[64 * 65];
    if (blockIdx.y >= 17) {
        const int t = (blockIdx.y - 17) * 32 + blockIdx.x;
        tp_dispatch(t, wqN, wkN, wvN, woN, w1N, w2N,
                    WTqkvN, WTwoN, WTw1N, WTw2N, (float(*)[65])smem);
        return;
    }
    u16* lds = (u16*)smem;
    const int N = DFFD, K = DD;
    const int tid = threadIdx.x, wid = tid >> 6, lane = tid & 63;
    const int m0 = blockIdx.y * 128, n0 = blockIdx.x * 128;
    const int wm = (wid >> 1) * 64, wn = (wid & 1) * 64;
    const int srow = lane >> 2, scol = (lane & 3) * 8;
    const int l15 = lane & 15, loct = lane >> 4;

    f32x4 acc[4][4] = {};
    const size_t arow = (size_t)(m0 + wid * 16 + srow) * K + scol;
    const size_t brow = (size_t)(n0 + wid * 16 + srow) * K + scol;
    u16* ldsA = lds + wid * 512;
    u16* ldsB = lds + 4096 + wid * 512;

    for (int k0 = 0; k0 < K; k0 += 32) {
        __builtin_amdgcn_global_load_lds(GLB(A  + arow + k0),                 LDSP(ldsA),        16, 0, 0);
        __builtin_amdgcn_global_load_lds(GLB(A  + arow + (size_t)64*K + k0),  LDSP(ldsA + 2048), 16, 0, 0);
        __builtin_amdgcn_global_load_lds(GLB(BT + brow + k0),                 LDSP(ldsB),        16, 0, 0);
        __builtin_amdgcn_global_load_lds(GLB(BT + brow + (size_t)64*K + k0),  LDSP(ldsB + 2048), 16, 0, 0);
        __syncthreads();
        bf16x8 af[4], bfr[4];
        #pragma unroll
        for (int i = 0; i < 4; ++i)
            af[i] = *(const bf16x8*)(lds + (wm + i * 16 + l15) * 32 + loct * 8);
        #pragma unroll
        for (int j = 0; j < 4; ++j)
            bfr[j] = *(const bf16x8*)(lds + 4096 + (wn + j * 16 + l15) * 32 + loct * 8);
        #pragma unroll
        for (int i = 0; i < 4; ++i)
            #pragma unroll
            for (int j = 0; j < 4; ++j)
                acc[i][j] = __builtin_amdgcn_mfma_f32_16x16x32_bf16(af[i], bfr[j], acc[i][j], 0, 0, 0);
        __syncthreads();
    }

    #pragma unroll
    for (int j = 0; j < 4; ++j) {
        const int col = n0 + wn + j * 16 + l15;
        const float bv = bias[col];
        #pragma unroll
        for (int i = 0; i < 4; ++i) {
            const int rbase = m0 + wm + i * 16 + loct * 4;
            #pragma unroll
            for (int r = 0; r < 4; ++r) {
                const int row = rbase + r;
                if (row < M) {
                    float v = acc[i][j][r] + bv;
                    v = 0.5f * v * (1.f + erff(v * 0.70710678118654752f));
                    Cout[(size_t)row * N + col] = f2bf(v);
                }
            }
        }
    }
}

// =====================================================================
// Split-K bf16 MFMA GEMM, 128x128 tile, BK=32, SPLIT z-blocks over K.
// Writes fp32 partials to P[z][M][N] (combine fused into next ln).
// =====================================================================
template<int SPLIT>
__global__ __launch_bounds__(256) void gemm128_skp(
    const u16* __restrict__ A, const u16* __restrict__ BT,
    float* __restrict__ P, int M, int N, int K)
{
    __shared__ u16 lds[8192];
    const int tid = threadIdx.x, wid = tid >> 6, lane = tid & 63;
    const int m0 = blockIdx.y * 128, n0 = blockIdx.x * 128;
    const int wm = (wid >> 1) * 64, wn = (wid & 1) * 64;
    const int srow = lane >> 2, scol = (lane & 3) * 8;
    const int l15 = lane & 15, loct = lane >> 4;
    const int Ks = K / SPLIT;
    const int kb = blockIdx.z * Ks;

    f32x4 acc[4][4] = {};
    const size_t arow = (size_t)(m0 + wid * 16 + srow) * K + scol + kb;
    const size_t brow = (size_t)(n0 + wid * 16 + srow) * K + scol + kb;
    u16* ldsA = lds + wid * 512;
    u16* ldsB = lds + 4096 + wid * 512;

    for (int k0 = 0; k0 < Ks; k0 += 32) {
        __builtin_amdgcn_global_load_lds(GLB(A  + arow + k0),                 LDSP(ldsA),        16, 0, 0);
        __builtin_amdgcn_global_load_lds(GLB(A  + arow + (size_t)64*K + k0),  LDSP(ldsA + 2048), 16, 0, 0);
        __builtin_amdgcn_global_load_lds(GLB(BT + brow + k0),                 LDSP(ldsB),        16, 0, 0);
        __builtin_amdgcn_global_load_lds(GLB(BT + brow + (size_t)64*K + k0),  LDSP(ldsB + 2048), 16, 0, 0);
        __syncthreads();
        bf16x8 af[4], bfr[4];
        #pragma unroll
        for (int i = 0; i < 4; ++i)
            af[i] = *(const bf16x8*)(lds + (wm + i * 16 + l15) * 32 + loct * 8);
        #pragma unroll
        for (int j = 0; j < 4; ++j)
            bfr[j] = *(const bf16x8*)(lds + 4096 + (wn + j * 16 + l15) * 32 + loct * 8);
        #pragma unroll
        for (int i = 0; i < 4; ++i)
            #pragma unroll
            for (int j = 0; j < 4; ++j)
                acc[i][j] = __builtin_amdgcn_mfma_f32_16x16x32_bf16(af[i], bfr[j], acc[i][j], 0, 0, 0);
        __syncthreads();
    }

    float* Pz = P + (size_t)blockIdx.z * M * N;
    #pragma unroll
    for (int j = 0; j < 4; ++j) {
        const int col = n0 + wn + j * 16 + l15;
        #pragma unroll
        for (int i = 0; i < 4; ++i) {
            const int rbase = m0 + wm + i * 16 + loct * 4;
            #pragma unroll
            for (int r = 0; r < 4; ++r) {
                const int row = rbase + r;
                if (row < M) Pz[(size_t)row * N + col] = acc[i][j][r];
            }
        }
    }
}

// =====================================================================
// QKV GEMM: 128x128 mainloop, N=3072, bias select fused.
// Epilogue: cols < 2048 -> QKb [row][2048] (q|k), coalesced bf16.
//           cols >= 2048 (V): in-block LDS transpose ->
//           VTg [(b*1024+hd)][KPAD] at col=key, coalesced along key.
// =====================================================================
__global__ __launch_bounds__(256) void gemm_qkv(
    const u16* __restrict__ A, const u16* __restrict__ BT,
    const float* __restrict__ bq, const float* __restrict__ bk,
    const float* __restrict__ bvp,
    u16* __restrict__ QKb, u16* __restrict__ VTg, int M, int K)
{
    __shared__ u16 lds[128 * 66];          // 16.9 KB (mainloop uses first 16 KB)
    const int tid = threadIdx.x, wid = tid >> 6, lane = tid & 63;
    const int m0 = blockIdx.y * 128, n0 = blockIdx.x * 128;
    const int wm = (wid >> 1) * 64, wn = (wid & 1) * 64;
    const int srow = lane >> 2, scol = (lane & 3) * 8;
    const int l15 = lane & 15, loct = lane >> 4;

    f32x4 acc[4][4] = {};
    const size_t arow = (size_t)(m0 + wid * 16 + srow) * K + scol;
    const size_t brow = (size_t)(n0 + wid * 16 + srow) * K + scol;
    u16* ldsA = lds + wid * 512;
    u16* ldsB = lds + 4096 + wid * 512;

    for (int k0 = 0; k0 < K; k0 += 32) {
        __builtin_amdgcn_global_load_lds(GLB(A  + arow + k0),                 LDSP(ldsA),        16, 0, 0);
        __builtin_amdgcn_global_load_lds(GLB(A  + arow + (size_t)64*K + k0),  LDSP(ldsA + 2048), 16, 0, 0);
        __builtin_amdgcn_global_load_lds(GLB(BT + brow + k0),                 LDSP(ldsB),        16, 0, 0);
        __builtin_amdgcn_global_load_lds(GLB(BT + brow + (size_t)64*K + k0),  LDSP(ldsB + 2048), 16, 0, 0);
        __syncthreads();
        bf16x8 af[4], bfr[4];
        #pragma unroll
        for (int i = 0; i < 4; ++i)
            af[i] = *(const bf16x8*)(lds + (wm + i * 16 + l15) * 32 + loct * 8);
        #pragma unroll
        for (int j = 0; j < 4; ++j)
            bfr[j] = *(const bf16x8*)(lds + 4096 + (wn + j * 16 + l15) * 32 + loct * 8);
        #pragma unroll
        for (int i = 0; i < 4; ++i)
            #pragma unroll
            for (int j = 0; j < 4; ++j)
                acc[i][j] = __builtin_amdgcn_mfma_f32_16x16x32_bf16(af[i], bfr[j], acc[i][j], 0, 0, 0);
        __syncthreads();
    }

    if (n0 < 2048) {
        // ---- Q|K epilogue: coalesced row-major bf16 ----
        #pragma unroll
        for (int j = 0; j < 4; ++j) {
            const int col = n0 + wn + j * 16 + l15;
            const float bval = (col < 1024) ? bq[col] : bk[col - 1024];
            #pragma unroll
            for (int i = 0; i < 4; ++i) {
                const int rbase = m0 + wm + i * 16 + loct * 4;
                #pragma unroll
                for (int r = 0; r < 4; ++r) {
                    const int row = rbase + r;
                    if (row < M)
                        QKb[(size_t)row * 2048 + col] = f2bf(acc[i][j][r] + bval);
                }
            }
        }
    } else {
        // ---- V epilogue: transpose 128x128 tile via LDS, 2 col-halves ----
        const int hd0 = n0 - 2048;
        #pragma unroll
        for (int h = 0; h < 2; ++h) {
            __syncthreads();
            if ((wn >> 6) == h) {
                #pragma unroll
                for (int j = 0; j < 4; ++j) {
                    const int c = j * 16 + l15;                  // 0..63
                    const float bval = bvp[hd0 + h * 64 + c];
                    #pragma unroll
                    for (int i = 0; i < 4; ++i) {
                        const int rbase = wm + i * 16 + loct * 4;
                        #pragma unroll
                        for (int r = 0; r < 4; ++r)
                            lds[(rbase + r) * 66 + c] = f2bf(acc[i][j][r] + bval);
                    }
                }
            }
            __syncthreads();
            const int rowLane = tid & 63, cIdx = tid >> 6;
            #pragma unroll
            for (int cc = 0; cc < 16; ++cc) {
                const int c = cIdx * 16 + cc;                    // 0..63
                #pragma unroll
                for (int rh = 0; rh < 2; ++rh) {
                    const int row = rowLane + rh * 64;
                    const int g = m0 + row;
                    if (g < M) {
                        const int b = g / SD, key = g - b * SD;
                        VTg[((size_t)b * 1024 + hd0 + h * 64 + c) * KPAD + key] =
                            lds[row * 66 + c];
                    }
                }
            }
        }
    }
}

// =====================================================================
// Patch-embed carrier: gemm64 fp32-out (grid y<32; M=MPAT,N=DD,K=512)
// + layer-0 weight transpose tiles (grid y in [32,224)).
// =====================================================================
__global__ __launch_bounds__(256) void patch_tp(
    const u16* __restrict__ A, const u16* __restrict__ BT,
    const float* __restrict__ bias, float* __restrict__ Cout,
    const float* __restrict__ wq0, const float* __restrict__ wk0,
    const float* __restrict__ wv0, const float* __restrict__ wo0,
    const float* __restrict__ w10, const float* __restrict__ w20,
    u16* __restrict__ WTqkv0, u16* __restrict__ WTwo0,
    u16* __restrict__ WTw10, u16* __restrict__ WTw20)
{
    __shared__ float smem[64 * 65];
    if (blockIdx.y >= 32) {
        const int t = (blockIdx.y - 32) * 16 + blockIdx.x;
        tp_dispatch(t, wq0, wk0, wv0, wo0, w10, w20,
                    WTqkv0, WTwo0, WTw10, WTw20, (float(*)[65])smem);
        return;
    }
    u16* lds = (u16*)smem;
    const int N = DD, K = 512;
    const int tid = threadIdx.x, wid = tid >> 6, lane = tid & 63;
    const int m0 = blockIdx.y * 64, n0 = blockIdx.x * 64;
    const int wm = (wid >> 1) * 32, wn = (wid & 1) * 32;
    const int srow = lane >> 2, scol = (lane & 3) * 8;
    const int l15 = lane & 15, loct = lane >> 4;

    f32x4 acc[2][2] = {};
    const size_t arow = (size_t)(m0 + wid * 16 + srow) * K + scol;
    const size_t brow = (size_t)(n0 + wid * 16 + srow) * K + scol;
    u16* ldsA = lds + wid * 512;
    u16* ldsB = lds + 4096 + wid * 512;

    for (int k0 = 0; k0 < K; k0 += 64) {
        __builtin_amdgcn_global_load_lds(GLB(A  + arow + k0),      LDSP(ldsA),        16, 0, 0);
        __builtin_amdgcn_global_load_lds(GLB(A  + arow + k0 + 32), LDSP(ldsA + 2048), 16, 0, 0);
        __builtin_amdgcn_global_load_lds(GLB(BT + brow + k0),      LDSP(ldsB),        16, 0, 0);
        __builtin_amdgcn_global_load_lds(GLB(BT + brow + k0 + 32), LDSP(ldsB + 2048), 16, 0, 0);
        __syncthreads();
        #pragma unroll
        for (int t = 0; t < 2; ++t) {
            bf16x8 af[2], bfr[2];
            #pragma unroll
            for (int i = 0; i < 2; ++i)
                af[i] = *(const bf16x8*)(lds + t * 2048 + (wm + i * 16 + l15) * 32 + loct * 8);
            #pragma unroll
            for (int j = 0; j < 2; ++j)
                bfr[j] = *(const bf16x8*)(lds + 4096 + t * 2048 + (wn + j * 16 + l15) * 32 + loct * 8);
            #pragma unroll
            for (int i = 0; i < 2; ++i)
                #pragma unroll
                for (int j = 0; j < 2; ++j)
                    acc[i][j] = __builtin_amdgcn_mfma_f32_16x16x32_bf16(af[i], bfr[j], acc[i][j], 0, 0, 0);
        }
        __syncthreads();
    }

    #pragma unroll
    for (int j = 0; j < 2; ++j) {
        const int col = n0 + wn + j * 16 + l15;
        const float bv = bias[col];
        #pragma unroll
        for (int i = 0; i < 2; ++i) {
            const int rbase = m0 + wm + i * 16 + loct * 4;
            #pragma unroll
            for (int r = 0; r < 4; ++r) {
                const int row = rbase + r;
                Cout[(size_t)row * N + col] = acc[i][j][r] + bv;
            }
        }
    }
}

// =====================================================================
// bf16 MFMA GEMM, 64x64 tile, BK=64 (proj, predictor).
// =====================================================================
template<int ACT, int OBF>
__global__ __launch_bounds__(256) void gemm64(
    const u16* __restrict__ A, const u16* __restrict__ BT,
    const float* __restrict__ bias, const float* __restrict__ Cin,
    void* __restrict__ Cout, int M, int N, int K)
{
    __shared__ u16 lds[8192];
    const int tid = threadIdx.x, wid = tid >> 6, lane = tid & 63;
    const int m0 = blockIdx.y * 64, n0 = blockIdx.x * 64;
    const int wm = (wid >> 1) * 32, wn = (wid & 1) * 32;
    const int srow = lane >> 2, scol = (lane & 3) * 8;
    const int l15 = lane & 15, loct = lane >> 4;

    f32x4 acc[2][2] = {};
    const size_t arow = (size_t)(m0 + wid * 16 + srow) * K + scol;
    const size_t brow = (size_t)(n0 + wid * 16 + srow) * K + scol;
    u16* ldsA = lds + wid * 512;
    u16* ldsB = lds + 4096 + wid * 512;

    for (int k0 = 0; k0 < K; k0 += 64) {
        __builtin_amdgcn_global_load_lds(GLB(A  + arow + k0),      LDSP(ldsA),        16, 0, 0);
        __builtin_amdgcn_global_load_lds(GLB(A  + arow + k0 + 32), LDSP(ldsA + 2048), 16, 0, 0);
        __builtin_amdgcn_global_load_lds(GLB(BT + brow + k0),      LDSP(ldsB),        16, 0, 0);
        __builtin_amdgcn_global_load_lds(GLB(BT + brow + k0 + 32), LDSP(ldsB + 2048), 16, 0, 0);
        __syncthreads();
        #pragma unroll
        for (int t = 0; t < 2; ++t) {
            bf16x8 af[2], bfr[2];
            #pragma unroll
            for (int i = 0; i < 2; ++i)
                af[i] = *(const bf16x8*)(lds + t * 2048 + (wm + i * 16 + l15) * 32 + loct * 8);
            #pragma unroll
            for (int j = 0; j < 2; ++j)
                bfr[j] = *(const bf16x8*)(lds + 4096 + t * 2048 + (wn + j * 16 + l15) * 32 + loct * 8);
            #pragma unroll
            for (int i = 0; i < 2; ++i)
                #pragma unroll
                for (int j = 0; j < 2; ++j)
                    acc[i][j] = __builtin_amdgcn_mfma_f32_16x16x32_bf16(af[i], bfr[j], acc[i][j], 0, 0, 0);
        }
        __syncthreads();
    }

    #pragma unroll
    for (int j = 0; j < 2; ++j) {
        const int col = n0 + wn + j * 16 + l15;
        const float bv = bias[col];
        #pragma unroll
        for (int i = 0; i < 2; ++i) {
            const int rbase = m0 + wm + i * 16 + loct * 4;
            #pragma unroll
            for (int r = 0; r < 4; ++r) {
                const int row = rbase + r;
                if (row < M) {
                    float v = acc[i][j][r] + bv;
                    if (ACT) v = 0.5f * v * (1.f + erff(v * 0.70710678118654752f));
                    if (Cin) v += Cin[(size_t)row * N + col];
                    if (OBF) ((u16*)Cout)[(size_t)row * N + col] = f2bf(v);
                    else     ((float*)Cout)[(size_t)row * N + col] = v;
                }
            }
        }
    }
}

// =====================================================================
// Fused attention, one (b,h) per blockIdx.x, 64 q-rows per block.
// QKb bf16 [2056][2048] (q|k per head at h*64).
// =====================================================================
__global__ __launch_bounds__(256) void attn_fused(
    const u16* __restrict__ QKb, const u16* __restrict__ VTg,
    u16* __restrict__ O)
{
    __shared__ u16 P[4][16][296];          // 37.9 KB
    const int tid = threadIdx.x, wid = tid >> 6, lane = tid & 63;
    const int l15 = lane & 15, loct = lane >> 4;
    const int bh = blockIdx.x, b = bh >> 4, h = bh & 15;
    const int q0 = blockIdx.y * 64 + wid * 16;

    const size_t qkbase = (size_t)b * SD * 2048 + h * 64;
    const u16* qp = QKb + qkbase + (size_t)imin(q0 + l15, SD - 1) * 2048;
    const bf16x8 qf0 = *(const bf16x8*)(qp + loct * 8);
    const bf16x8 qf1 = *(const bf16x8*)(qp + 32 + loct * 8);

    f32x4 s[17];
    #pragma unroll
    for (int nt = 0; nt < 17; ++nt) {
        const u16* kp = QKb + qkbase + (size_t)imin(nt * 16 + l15, SD - 1) * 2048 + 1024;
        const bf16x8 kf0 = *(const bf16x8*)(kp + loct * 8);
        const bf16x8 kf1 = *(const bf16x8*)(kp + 32 + loct * 8);
        f32x4 a = {};
        a = __builtin_amdgcn_mfma_f32_16x16x32_bf16(qf0, kf0, a, 0, 0, 0);
        a = __builtin_amdgcn_mfma_f32_16x16x32_bf16(qf1, kf1, a, 0, 0, 0);
        s[nt] = a;
    }

    const float dec = logf(1.f - exp2f(-1.f - (float)h));
    const int qb = q0 + loct * 4;
    float rmax[4] = {-3.4e38f, -3.4e38f, -3.4e38f, -3.4e38f};
    #pragma unroll
    for (int nt = 0; nt < 17; ++nt) {
        const int key = nt * 16 + l15;
        #pragma unroll
        for (int r = 0; r < 4; ++r) {
            float v;
            if (key >= SD) {
                v = -1e30f;
            } else {
                v = s[nt][r] * 0.125f;
                const int q = qb + r;
                if (q > 0 && key > 0) {
                    const int nq = q - 1, nk = key - 1;
                    const int dist = abs((nq >> 4) - (nk >> 4)) + abs((nq & 15) - (nk & 15));
                    v += dec * (float)dist;
                }
            }
            s[nt][r] = v;
            rmax[r] = fmaxf(rmax[r], v);
        }
    }
    #pragma unroll
    for (int r = 0; r < 4; ++r) {
        #pragma unroll
        for (int m = 1; m < 16; m <<= 1) rmax[r] = fmaxf(rmax[r], __shfl_xor(rmax[r], m));
    }
    float rsum[4] = {0.f, 0.f, 0.f, 0.f};
    #pragma unroll
    for (int nt = 0; nt < 17; ++nt)
        #pragma unroll
        for (int r = 0; r < 4; ++r) {
            const float e = __expf(s[nt][r] - rmax[r]);
            s[nt][r] = e;
            rsum[r] += e;
        }
    #pragma unroll
    for (int r = 0; r < 4; ++r) {
        #pragma unroll
        for (int m = 1; m < 16; m <<= 1) rsum[r] += __shfl_xor(rsum[r], m);
        rsum[r] = 1.f / rsum[r];
    }
    #pragma unroll
    for (int nt = 0; nt < 17; ++nt)
        #pragma unroll
        for (int r = 0; r < 4; ++r)
            P[wid][loct * 4 + r][nt * 16 + l15] = f2bf(s[nt][r] * rsum[r]);
    {
        const int rr = lane >> 2, cc = (lane & 3) * 4;
        #pragma unroll
        for (int i = 0; i < 4; ++i) P[wid][rr][272 + cc + i] = 0;
    }

    f32x4 o[4] = {};
    const u16* vrow = VTg + ((size_t)b * 1024 + h * 64) * KPAD;
    #pragma unroll
    for (int ks = 0; ks < 9; ++ks) {
        const bf16x8 pf = *(const bf16x8*)&P[wid][l15][ks * 32 + loct * 8];
        #pragma unroll
        for (int j = 0; j < 4; ++j) {
            const bf16x8 vf = *(const bf16x8*)(vrow + (size_t)(j * 16 + l15) * KPAD + ks * 32 + loct * 8);
            o[j] = __builtin_amdgcn_mfma_f32_16x16x32_bf16(pf, vf, o[j], 0, 0, 0);
        }
    }
    #pragma unroll
    for (int j = 0; j < 4; ++j)
        #pragma unroll
        for (int r = 0; r < 4; ++r) {
            const int q = qb + r;
            if (q < SD) O[((size_t)(b * SD + q)) * DD + h * 64 + j * 16 + l15] = f2bf(o[j][r]);
        }
}

// =====================================================================
// Standalone batched 64x64 transpose (prologue: patch_w, enpred_w).
// =====================================================================
__global__ __launch_bounds__(256) void transpose_bf16_b(
    const float* __restrict__ W, u16* __restrict__ WT, int K, int N,
    size_t sstrideZ, size_t dstrideZ)
{
    __shared__ float t[64][65];
    tp64(W + (size_t)blockIdx.z * sstrideZ, WT + (size_t)blockIdx.z * dstrideZ,
         K, N, blockIdx.y * 64, blockIdx.x * 64, t);
}

__global__ __launch_bounds__(256) void im2col_k(const float* __restrict__ imgs,
                                                u16* __restrict__ Ao)
{
    const int idx = blockIdx.x * 256 + threadIdx.x;
    const int k = idx & 511, m = idx >> 9;
    const int b = m >> 8, n = m & 255;
    const int hp = n >> 4, wp = n & 15;
    const int c = k >> 8, p = (k >> 4) & 15, q = k & 15;
    Ao[idx] = f2bf(imgs[(((size_t)b * CCH + c) * IMGD + hp * PDIM + p) * IMGD + wp * PDIM + q]);
}

__global__ __launch_bounds__(256) void build_x_k(const float* __restrict__ RES,
                                                 const float* __restrict__ cls,
                                                 float* __restrict__ X)
{
    const int idx = blockIdx.x * 256 + threadIdx.x;
    const int d = idx & 1023;
    const int r = idx >> 10;
    const int b = r / SD;
    const int s = r - b * SD;
    X[idx] = (s == 0) ? cls[d] : RES[((size_t)(b * NTOK + s - 1)) * DD + d];
}

// =====================================================================
// LayerNorm, one wave per row, 4 rows/block. NP>0: first combine
// X += badd + sum(partials) (split-K MLP2 reduction fused in), write X.
// =====================================================================
template<int NP, int OBF>
__global__ __launch_bounds__(256) void ln_rows_c(
    float* __restrict__ X, const float* __restrict__ PB, size_t pstride,
    const float* __restrict__ badd,
    const float* __restrict__ w, const float* __restrict__ bsrc,
    void* __restrict__ Y)
{
    const int wid = threadIdx.x >> 6, lane = threadIdx.x & 63;
    const int row = blockIdx.x * 4 + wid;
    float* xr = X + (size_t)row * DD;
    float4 v[4];
    float s = 0.f, s2 = 0.f;
    #pragma unroll
    for (int i = 0; i < 4; ++i) {
        const int cc = (i * 64 + lane) * 4;
        v[i] = *(const float4*)(xr + cc);
        if (NP) {
            const float4 bb = *(const float4*)(badd + cc);
            v[i].x += bb.x; v[i].y += bb.y; v[i].z += bb.z; v[i].w += bb.w;
            #pragma unroll
            for (int p = 0; p < NP; ++p) {
                const float4 pv = *(const float4*)(PB + (size_t)p * pstride + (size_t)row * DD + cc);
                v[i].x += pv.x; v[i].y += pv.y; v[i].z += pv.z; v[i].w += pv.w;
            }
            *(float4*)(xr + cc) = v[i];
        }
        s  += v[i].x + v[i].y + v[i].z + v[i].w;
        s2 += v[i].x * v[i].x + v[i].y * v[i].y + v[i].z * v[i].z + v[i].w * v[i].w;
    }
    #pragma unroll
    for (int off = 1; off < 64; off <<= 1) {
        s  += __shfl_xor(s, off);
        s2 += __shfl_xor(s2, off);
    }
    const float mu  = s * (1.f / 1024.f);
    const float var = fmaf(-mu, mu, s2 * (1.f / 1024.f));
    const float ri  = rsqrtf(var + 1e-5f);
    #pragma unroll
    for (int i = 0; i < 4; ++i) {
        const int cc = (i * 64 + lane) * 4;
        const float4 wv = *(const float4*)(w + cc);
        const float4 bv = *(const float4*)(bsrc + cc);
        float4 o;
        o.x = (v[i].x - mu) * ri * wv.x + bv.x;
        o.y = (v[i].y - mu) * ri * wv.y + bv.y;
        o.z = (v[i].z - mu) * ri * wv.z + bv.z;
        o.w = (v[i].w - mu) * ri * wv.w + bv.w;
        if (OBF) {
            ushort4 o4 = make_ushort4(f2bf(o.x), f2bf(o.y), f2bf(o.z), f2bf(o.w));
            *(ushort4*)((u16*)Y + (size_t)row * DD + cc) = o4;
        } else {
            *(float4*)((float*)Y + (size_t)row * DD + cc) = o;
        }
    }
}

// =====================================================================
// PGSA, coalesced: block = (32-channel group, batch). Thread owns one
// channel x 32 tokens in registers. Single pass: tot2 = s2 - s^2/256.
// =====================================================================
__global__ __launch_bounds__(256) void pgsa_k(const float* __restrict__ Xf,
                                              const float* __restrict__ RES,
                                              u16* __restrict__ TOK)
{
    const int b = blockIdx.y, ch = blockIdx.x * 32 + (threadIdx.x & 31);
    const int r8 = threadIdx.x >> 5;       // 0..7
    float v[32];
    float s = 0.f, s2 = 0.f;
    #pragma unroll
    for (int it = 0; it < 32; ++it) {
        const int tok = it * 8 + r8;
        v[it] = Xf[((size_t)(b * SD + 1 + tok)) * DD + ch];
        s += v[it];
        s2 = fmaf(v[it], v[it], s2);
    }
    __shared__ float rs[8][32], rs2[8][32];
    rs[r8][threadIdx.x & 31] = s;
    rs2[r8][threadIdx.x & 31] = s2;
    __syncthreads();
    s = 0.f; s2 = 0.f;
    #pragma unroll
    for (int k = 0; k < 8; ++k) {
        s += rs[k][threadIdx.x & 31];
        s2 += rs2[k][threadIdx.x & 31];
    }
    const float mu = s * (1.f / 256.f);
    const float tot2 = fmaf(-mu, s, s2);   // s2 - 256*mu^2
    const float dinv = 1.f / (4.f * (tot2 * (1.f / 255.f) + 1e-4f));
    #pragma unroll
    for (int it = 0; it < 32; ++it) {
        const int tok = it * 8 + r8;
        const float xm = v[it] - mu;
        const float y = fmaf(xm * xm, dinv, 0.5f);
        const float sig = 1.f / (1.f + expf(-y));
        const size_t ri = ((size_t)b * NTOK + tok) * DD + ch;
        TOK[ri] = f2bf(fmaf(v[it], sig, RES[ri]));
    }
}

// =====================================================================
// Unpatchify: one thread per (b,i,j), reads float2 (both channels),
// writes both channel planes coalesced.
// =====================================================================
__global__ __launch_bounds__(256) void unpatch_k(const float* __restrict__ PRED,
                                                 float* __restrict__ out)
{
    const int idx = blockIdx.x * 256 + threadIdx.x;   // 0..524287
    const int j = idx & 255, i = (idx >> 8) & 255, b = idx >> 16;
    const int hp = i >> 4, p = i & 15, wp = j >> 4, q = j & 15;
    const float2 f2 = *(const float2*)&PRED[(((size_t)b * NTOK + hp * 16 + wp) * 512) + (p * 16 + q) * 2];
    const size_t o0 = (size_t)b * 131072 + (size_t)i * 256 + j;
    out[o0]         = f2.x;
    out[o0 + 65536] = f2.y;
}

// =====================================================================
extern "C" void kernel_launch(void* const* d_in, const int* in_sizes, int n_in,
                              void* d_out, int out_size, void* d_ws, size_t ws_size,
                              hipStream_t stream)
{
    const float* imgs     = (const float*)d_in[0];
    const float* patch_w  = (const float*)d_in[1];
    const float* patch_b  = (const float*)d_in[2];
    const float* cls_tok  = (const float*)d_in[3];
    const float* ln1_w    = (const float*)d_in[4];
    const float* ln1_b    = (const float*)d_in[5];
    const float* wq       = (const float*)d_in[6];
    const float* wk       = (const float*)d_in[7];
    const float* wv       = (const float*)d_in[8];
    const float* bq       = (const float*)d_in[9];
    const float* bk       = (const float*)d_in[10];
    const float* bv       = (const float*)d_in[11];
    const float* wo       = (const float*)d_in[12];
    const float* bo       = (const float*)d_in[13];
    const float* ln2_w    = (const float*)d_in[14];
    const float* ln2_b    = (const float*)d_in[15];
    const float* w1       = (const float*)d_in[16];
    const float* b1       = (const float*)d_in[17];
    const float* w2       = (const float*)d_in[18];
    const float* b2       = (const float*)d_in[19];
    const float* normf_w  = (const float*)d_in[20];
    const float* normf_b  = (const float*)d_in[21];
    const float* enpred_w = (const float*)d_in[22];
    const float* enpred_b = (const float*)d_in[23];
    float* out = (float*)d_out;

    // ---- workspace layout (~295 MB; ws = 512 MiB) ----
    char* w = (char*)d_ws;
    float* X     = (float*)w;            w += (size_t)MTOK * DD * 4;          //  8.42 MB
    float* RES   = (float*)w;            w += (size_t)MPAT * DD * 4;          //  8.39 MB
    u16*   QKb   = (u16*)w;              w += (size_t)MPAD * 2048 * 2;        //  8.91 MB (alias Hf fp32 8.42)
    u16*   VTg   = (u16*)w;              w += (size_t)BB * 1024 * KPAD * 2;   //  4.72 MB
    char*  UNION = w;                    w += (size_t)MPAD * DFFD * 2;        // 17.83 MB: im2col/GELUb/PRED
    u16*   Hb    = (u16*)w;              w += (size_t)MPAD * DD * 2;          //  4.46 MB (alias TOKb)
    u16*   Ob    = (u16*)w;              w += (size_t)MPAD * DD * 2;          //  4.46 MB
    float* PART  = (float*)w;            w += (size_t)4 * MTOK * DD * 4;      // 33.69 MB (split-K partials)
    u16*   WTqkv = (u16*)w;              w += (size_t)LLAY * 3072 * DD * 2;   // 50.33 MB
    u16*   WTwo  = (u16*)w;              w += (size_t)LLAY * DD * DD * 2;     // 16.78 MB
    u16*   WTw1  = (u16*)w;              w += (size_t)LLAY * DFFD * DD * 2;   // 67.11 MB
    u16*   WTw2  = (u16*)w;              w += (size_t)LLAY * DD * DFFD * 2;   // 67.11 MB
    u16*   WTpe  = (u16*)w;              w += (size_t)DD * 512 * 2;           //  1.05 MB
    u16*   WTen  = (u16*)w;              w += (size_t)512 * DD * 2;           //  1.05 MB

    u16*   IM2b  = (u16*)UNION;
    u16*   GELUb = (u16*)UNION;
    float* PRED  = (float*)UNION;
    float* Hf    = (float*)QKb;
    u16*   TOKb  = Hb;
    const size_t PSTR = (size_t)MTOK * DD;

    // zero VT pads once (gemm_qkv writes only keys 0..256 each layer)
    hipMemsetAsync(VTg, 0, (size_t)BB * 1024 * KPAD * 2, stream);

    // ---- prologue: small transposes + im2col ----
    hipLaunchKernelGGL(transpose_bf16_b, dim3(DD / 64, 512 / 64, 1), dim3(256), 0, stream,
                       patch_w, WTpe, 512, DD, (size_t)0, (size_t)0);
    hipLaunchKernelGGL(transpose_bf16_b, dim3(512 / 64, DD / 64, 1), dim3(256), 0, stream,
                       enpred_w, WTen, DD, 512, (size_t)0, (size_t)0);
    hipLaunchKernelGGL(im2col_k, dim3(4096), dim3(256), 0, stream, imgs, IM2b);

    // ---- patch embed carrier (gemm64 + layer-0 weight transposes) ----
    hipLaunchKernelGGL(patch_tp, dim3(DD / 64, 32 + 192), dim3(256), 0, stream,
                       IM2b, WTpe, patch_b, RES,
                       wq, wk, wv, wo, w1, w2,
                       WTqkv, WTwo, WTw1, WTw2);
    hipLaunchKernelGGL(build_x_k, dim3(MTOK * DD / 256), dim3(256), 0, stream, RES, cls_tok, X);

    // ---- transformer layers ----
    for (int i = 0; i < LLAY; ++i) {
        if (i == 0)
            hipLaunchKernelGGL((ln_rows_c<0,1>), dim3(MTOK / 4), dim3(256), 0, stream,
                               X, (const float*)nullptr, (size_t)0, (const float*)nullptr,
                               ln1_w + i * DD, ln1_b + i * DD, (void*)Hb);
        else
            hipLaunchKernelGGL((ln_rows_c<4,1>), dim3(MTOK / 4), dim3(256), 0, stream,
                               X, PART, PSTR, b2 + (i - 1) * DD,
                               ln1_w + i * DD, ln1_b + i * DD, (void*)Hb);
        hipLaunchKernelGGL(gemm_qkv, dim3(3072 / 128, 17), dim3(256), 0, stream,
                           Hb, WTqkv + (size_t)i * 3072 * DD,
                           bq + i * DD, bk + i * DD, bv + i * DD, QKb, VTg, MTOK, DD);
        hipLaunchKernelGGL(attn_fused, dim3(BB * NHEAD, 5), dim3(256), 0, stream,
                           QKb, VTg, Ob);
        hipLaunchKernelGGL((gemm64<0,0>), dim3(DD / 64, 33), dim3(256), 0, stream,
                           Ob, WTwo + (size_t)i * DD * DD, bo + i * DD, X, (void*)X, MTOK, DD, DD);
        hipLaunchKernelGGL((ln_rows_c<0,1>), dim3(MTOK / 4), dim3(256), 0, stream,
                           X, (const float*)nullptr, (size_t)0, (const float*)nullptr,
                           ln2_w + i * DD, ln2_b + i * DD, (void*)Hb);
        if (i < LLAY - 1) {
            const size_t n1 = (size_t)(i + 1);
            hipLaunchKernelGGL(mlp1_tp, dim3(DFFD / 128, 17 + 96), dim3(256), 0, stream,
                               Hb, WTw1 + (size_t)i * DFFD * DD, b1 + i * DFFD, GELUb, MTOK,
                               wq + n1 * DD * DD, wk + n1 * DD * DD, wv + n1 * DD * DD,
                               wo + n1 * DD * DD, w1 + n1 * DD * DFFD, w2 + n1 * DFFD * DD,
                               WTqkv + n1 * 3072 * DD, WTwo + n1 * DD * DD,
                               WTw1 + n1 * DFFD * DD, WTw2 + n1 * DD * DFFD);
        } else {
            hipLaunchKernelGGL(mlp1_tp, dim3(DFFD / 128, 17), dim3(256), 0, stream,
                               Hb, WTw1 + (size_t)i * DFFD * DD, b1 + i * DFFD, GELUb, MTOK,
                               (const float*)nullptr, (const float*)nullptr, (const float*)nullptr,
                               (const float*)nullptr, (const float*)nullptr, (const float*)nullptr,
                               (u16*)nullptr, (u16*)nullptr, (u16*)nullptr, (u16*)nullptr);
        }
        hipLaunchKernelGGL((gemm128_skp<4>), dim3(DD / 128, 17, 4), dim3(256), 0, stream,
                           GELUb, WTw2 + (size_t)i * DD * DFFD, PART, MTOK, DD, DFFD);
    }

    // ---- final LN (combines layer-7 MLP2) + PGSA + predictor + unpatchify ----
    hipLaunchKernelGGL((ln_rows_c<4,0>), dim3(MTOK / 4), dim3(256), 0, stream,
                       X, PART, PSTR, b2 + (LLAY - 1) * DD, normf_w, normf_b, (void*)Hf);
    hipLaunchKernelGGL(pgsa_k, dim3(32, BB), dim3(256), 0, stream, Hf, RES, TOKb);
    hipLaunchKernelGGL((gemm64<0,0>), dim3(512 / 64, MPAT / 64), dim3(256), 0, stream,
                       TOKb, WTen, enpred_b, (const float*)nullptr, (void*)PRED, MPAT, 512, DD);
    hipLaunchKernelGGL(unpatch_k, dim3(2048), dim3(256), 0, stream, PRED, out);
}